// Round 14
// baseline (404.941 us; speedup 1.0000x reference)
//
#include <hip/hip_runtime.h>
#include <hip/hip_bf16.h>

typedef unsigned short u16;
typedef short short8 __attribute__((ext_vector_type(8)));
typedef short short4v __attribute__((ext_vector_type(4)));
typedef float f32x4 __attribute__((ext_vector_type(4)));

#define T_TOK 25088   // 128*196
#define NTOK 196
// 16B-chunk XOR swizzle (T2-style)
#define SWZ(r, c) ((((((c) >> 3) ^ ((r) & 7)) << 3)) | ((c) & 7))
// 8B-chunk XOR swizzle (Hs: packed ushort4 writes + paired b64 reads)
#define SWZ4(r, c) ((((((c) >> 2) & 16) | ((((c) >> 2) ^ (r)) & 15)) << 2) | ((c) & 3))

__device__ __forceinline__ u16 bfbits(float v) {
  __hip_bfloat16 h = __float2bfloat16(v);
  return *reinterpret_cast<u16*>(&h);
}
__device__ __forceinline__ float b2f(u16 u) {
  __hip_bfloat16 h = *reinterpret_cast<__hip_bfloat16*>(&u);
  return __bfloat162float(h);
}
// near-fp32 as hi+lo bf16 pair (Ootomo split)
__device__ __forceinline__ void fsplit(float v, u16& hi, u16& lo) {
  hi = bfbits(v);
  lo = bfbits(v - b2f(hi));
}

// ---------------------------------------------------------------------------
// Dense GEMM (r9/r11): C[M,N] = A[M,K] @ (Bh+Bl)[N,K]^T + bias.
// A split (3 MFMA/frag) when SPLITA — router-input path (wo).
// 128x128 tile, BK=32, 256 threads (4 waves 2x2), reg-staged 1-deep prefetch.
// EPI: 2 +resid->f32+bf16 | 5 ->bf16
// ---------------------------------------------------------------------------
template<int EPI, bool SPLITA>
__global__ __launch_bounds__(256) void gemm_bs(
    const u16* __restrict__ A, const u16* __restrict__ Al,
    const u16* __restrict__ Bh, const u16* __restrict__ Bl,
    int M, int N, int K,
    const float* __restrict__ bias, const float* __restrict__ extra,
    float* __restrict__ outf, u16* __restrict__ obh)
{
  __shared__ u16 As[128][40];                      // +8 pad: 2-way banks
  __shared__ u16 Asl[SPLITA ? 128 : 1][40];
  __shared__ u16 Bsh[128][40], Bsl[128][40];
  const int tid = threadIdx.x;
  const int lane = tid & 63, wave = tid >> 6;
  const int wm = wave >> 1, wn = wave & 1;
  const int row0 = blockIdx.x * 128, col0 = blockIdx.y * 128;

  const int r0 = tid >> 2, r1 = r0 + 64, co = (tid & 3) * 8;
  const int ar0 = row0 + r0, ar1 = row0 + r1;

  f32x4 acc[4][4];
  const f32x4 zero = {0.f, 0.f, 0.f, 0.f};
#pragma unroll
  for (int i = 0; i < 4; ++i)
#pragma unroll
    for (int j = 0; j < 4; ++j) acc[i][j] = zero;

  const int rsel = lane & 15, ksel = (lane >> 4) * 8;

  short8 ra, rl, rb0, rb1, rc0, rc1;
  auto issue = [&](int k0) {
    ra = *(const short8*)(A + (size_t)ar0 * K + k0 + co);
    rl = *(const short8*)(A + (size_t)ar1 * K + k0 + co);
    rb0 = *(const short8*)(Bh + (size_t)(col0 + r0) * K + k0 + co);
    rb1 = *(const short8*)(Bh + (size_t)(col0 + r1) * K + k0 + co);
    rc0 = *(const short8*)(Bl + (size_t)(col0 + r0) * K + k0 + co);
    rc1 = *(const short8*)(Bl + (size_t)(col0 + r1) * K + k0 + co);
  };
  short8 sa, sl;
  auto issueS = [&](int k0) {
    if constexpr (SPLITA) {
      sa = *(const short8*)(Al + (size_t)ar0 * K + k0 + co);
      sl = *(const short8*)(Al + (size_t)ar1 * K + k0 + co);
    }
  };
  auto commit = [&]() {
    *(short8*)&As[r0][co] = ra;
    *(short8*)&As[r1][co] = rl;
    if constexpr (SPLITA) {
      *(short8*)&Asl[r0][co] = sa;
      *(short8*)&Asl[r1][co] = sl;
    }
    *(short8*)&Bsh[r0][co] = rb0;
    *(short8*)&Bsh[r1][co] = rb1;
    *(short8*)&Bsl[r0][co] = rc0;
    *(short8*)&Bsl[r1][co] = rc1;
  };

  issue(0);
  issueS(0);
  commit();
  __syncthreads();

  for (int k0 = 0;;) {
    const bool more = (k0 + 32 < K);
    if (more) { issue(k0 + 32); issueS(k0 + 32); }
    short8 af[4], al4[4], bh4[4], bl4[4];
#pragma unroll
    for (int i = 0; i < 4; ++i) {
      af[i] = *(const short8*)&As[wm * 64 + i * 16 + rsel][ksel];
      if constexpr (SPLITA) al4[i] = *(const short8*)&Asl[wm * 64 + i * 16 + rsel][ksel];
    }
#pragma unroll
    for (int j = 0; j < 4; ++j) {
      bh4[j] = *(const short8*)&Bsh[wn * 64 + j * 16 + rsel][ksel];
      bl4[j] = *(const short8*)&Bsl[wn * 64 + j * 16 + rsel][ksel];
    }
#pragma unroll
    for (int i = 0; i < 4; ++i)
#pragma unroll
      for (int j = 0; j < 4; ++j) {
        acc[i][j] = __builtin_amdgcn_mfma_f32_16x16x32_bf16(af[i], bh4[j], acc[i][j], 0, 0, 0);
        if constexpr (SPLITA)
          acc[i][j] = __builtin_amdgcn_mfma_f32_16x16x32_bf16(al4[i], bh4[j], acc[i][j], 0, 0, 0);
        acc[i][j] = __builtin_amdgcn_mfma_f32_16x16x32_bf16(af[i], bl4[j], acc[i][j], 0, 0, 0);
      }
    k0 += 32;
    if (!more) break;
    __syncthreads();
    commit();
    __syncthreads();
  }

#pragma unroll
  for (int i = 0; i < 4; ++i) {
#pragma unroll
    for (int j = 0; j < 4; ++j) {
#pragma unroll
      for (int r = 0; r < 4; ++r) {
        int grow = row0 + wm * 64 + i * 16 + (lane >> 4) * 4 + r;   // token
        int gcol = col0 + wn * 64 + j * 16 + rsel;                  // feature
        float v = acc[i][j][r] + bias[gcol];
        size_t oi = (size_t)grow * N + gcol;
        if constexpr (EPI == 2) {
          v += extra[oi];                                  // residual
          outf[oi] = v;
          obh[oi] = bfbits(v);
        } else if constexpr (EPI == 5) {
          obh[oi] = bfbits(v);
        }
      }
    }
  }
}

// ---------------------------------------------------------------------------
// Patch-embed GEMM with FUSED im2col (r12): C = A(x) @ convW^T + b + pos.
// ---------------------------------------------------------------------------
__global__ __launch_bounds__(256) void gemm_patch(
    const float* __restrict__ xin,
    const u16* __restrict__ Bh, const u16* __restrict__ Bl,
    const float* __restrict__ bias, const float* __restrict__ pos,
    float* __restrict__ outf)
{
  __shared__ u16 As[128][40], Asl[128][40];
  __shared__ u16 Bsh[128][40], Bsl[128][40];
  const int tid = threadIdx.x;
  const int lane = tid & 63, wave = tid >> 6;
  const int wm = wave >> 1, wn = wave & 1;
  const int row0 = blockIdx.x * 128, col0 = blockIdx.y * 128;
  const int rsel = lane & 15, ksel = (lane >> 4) * 8;
  const int K = 768, N = 256;

  const int ar = tid >> 1, ph = tid & 1;
  const float* srcbase;
  {
    int t = row0 + ar;
    int b = t / 196, n = t - b * 196;
    int gh = n / 14, gw = n - gh * 14;
    srcbase = xin + ((size_t)(b * 3) * 224 + gh * 16) * 224 + gw * 16;
  }
  const int br0 = tid >> 2, br1 = br0 + 64, bco = (tid & 3) * 8;

  f32x4 acc[4][4];
  const f32x4 zero = {0.f, 0.f, 0.f, 0.f};
#pragma unroll
  for (int i = 0; i < 4; ++i)
#pragma unroll
    for (int j = 0; j < 4; ++j) acc[i][j] = zero;

  float4 fa0, fa1, fa2, fa3;
  short8 rb0, rb1, rc0, rc1;
  auto issue = [&](int k0) {
    int c = k0 >> 8, p = ((k0 >> 4) & 15) + ph;
    const float* s = srcbase + ((size_t)c * 224 + p) * 224;
    fa0 = *(const float4*)(s);
    fa1 = *(const float4*)(s + 4);
    fa2 = *(const float4*)(s + 8);
    fa3 = *(const float4*)(s + 12);
    rb0 = *(const short8*)(Bh + (size_t)(col0 + br0) * K + k0 + bco);
    rb1 = *(const short8*)(Bh + (size_t)(col0 + br1) * K + k0 + bco);
    rc0 = *(const short8*)(Bl + (size_t)(col0 + br0) * K + k0 + bco);
    rc1 = *(const short8*)(Bl + (size_t)(col0 + br1) * K + k0 + bco);
  };
  auto commit = [&]() {
    float f[16] = {fa0.x, fa0.y, fa0.z, fa0.w, fa1.x, fa1.y, fa1.z, fa1.w,
                   fa2.x, fa2.y, fa2.z, fa2.w, fa3.x, fa3.y, fa3.z, fa3.w};
    u16 hv[16], lv[16];
#pragma unroll
    for (int j = 0; j < 16; ++j) fsplit(f[j], hv[j], lv[j]);
    short8 h0 = {(short)hv[0], (short)hv[1], (short)hv[2], (short)hv[3],
                 (short)hv[4], (short)hv[5], (short)hv[6], (short)hv[7]};
    short8 h1 = {(short)hv[8], (short)hv[9], (short)hv[10], (short)hv[11],
                 (short)hv[12], (short)hv[13], (short)hv[14], (short)hv[15]};
    short8 l0 = {(short)lv[0], (short)lv[1], (short)lv[2], (short)lv[3],
                 (short)lv[4], (short)lv[5], (short)lv[6], (short)lv[7]};
    short8 l1 = {(short)lv[8], (short)lv[9], (short)lv[10], (short)lv[11],
                 (short)lv[12], (short)lv[13], (short)lv[14], (short)lv[15]};
    *(short8*)&As[ar][ph * 16] = h0;
    *(short8*)&As[ar][ph * 16 + 8] = h1;
    *(short8*)&Asl[ar][ph * 16] = l0;
    *(short8*)&Asl[ar][ph * 16 + 8] = l1;
    *(short8*)&Bsh[br0][bco] = rb0;
    *(short8*)&Bsh[br1][bco] = rb1;
    *(short8*)&Bsl[br0][bco] = rc0;
    *(short8*)&Bsl[br1][bco] = rc1;
  };

  issue(0);
  commit();
  __syncthreads();

  for (int k0 = 0;;) {
    const bool more = (k0 + 32 < K);
    if (more) issue(k0 + 32);
    short8 af[4], al4[4], bh4[4], bl4[4];
#pragma unroll
    for (int i = 0; i < 4; ++i) {
      af[i] = *(const short8*)&As[wm * 64 + i * 16 + rsel][ksel];
      al4[i] = *(const short8*)&Asl[wm * 64 + i * 16 + rsel][ksel];
    }
#pragma unroll
    for (int j = 0; j < 4; ++j) {
      bh4[j] = *(const short8*)&Bsh[wn * 64 + j * 16 + rsel][ksel];
      bl4[j] = *(const short8*)&Bsl[wn * 64 + j * 16 + rsel][ksel];
    }
#pragma unroll
    for (int i = 0; i < 4; ++i)
#pragma unroll
      for (int j = 0; j < 4; ++j) {
        acc[i][j] = __builtin_amdgcn_mfma_f32_16x16x32_bf16(af[i], bh4[j], acc[i][j], 0, 0, 0);
        acc[i][j] = __builtin_amdgcn_mfma_f32_16x16x32_bf16(al4[i], bh4[j], acc[i][j], 0, 0, 0);
        acc[i][j] = __builtin_amdgcn_mfma_f32_16x16x32_bf16(af[i], bl4[j], acc[i][j], 0, 0, 0);
      }
    k0 += 32;
    if (!more) break;
    __syncthreads();
    commit();
    __syncthreads();
  }

#pragma unroll
  for (int i = 0; i < 4; ++i) {
#pragma unroll
    for (int j = 0; j < 4; ++j) {
#pragma unroll
      for (int r = 0; r < 4; ++r) {
        int grow = row0 + wm * 64 + i * 16 + (lane >> 4) * 4 + r;   // token
        int gcol = col0 + wn * 64 + j * 16 + rsel;                  // feature
        float v = acc[i][j][r] + bias[gcol] + pos[(size_t)(grow % NTOK) * N + gcol];
        outf[(size_t)grow * N + gcol] = v;
      }
    }
  }
}

// ---------------------------------------------------------------------------
// Fused MoE v6: r12 structure (SWZ4 Hs) + ph1 restaged as 2 x BK=128 flat
// (16 MFMA per barrier window, 8 barriers/hc instead of 9) + setprio (T5).
// 64-token tiles, hi-only weights, 80 KB LDS, 2 blocks/CU, 8 waves.
// ---------------------------------------------------------------------------
__global__ __launch_bounds__(512, 4) void moe_fused(
    const u16* __restrict__ x1h,
    const u16* __restrict__ w1, const u16* __restrict__ w2,
    const float* __restrict__ b1, const float* __restrict__ b2,
    const float* __restrict__ gates,
    const int* __restrict__ idx_all, const int* __restrict__ cnt_all,
    const int* __restrict__ base_all,
    float* __restrict__ yslot)
{
  const int e = blockIdx.z;
  const int Meff = cnt_all[e];
  const int row0 = blockIdx.x * 64;
  if (row0 >= Meff) return;
  const int* gidx = idx_all + (size_t)e * T_TOK;
  const int hbase = base_all[e];
  const u16* W1 = w1 + (size_t)e * 262144;   // [1024][256] (n,k)
  const u16* W2 = w2 + (size_t)e * 262144;   // [256][1024] (n,k)
  const float* B1 = b1 + e * 1024;
  const float* B2 = b2 + e * 256;

  __shared__ u16 Xs[64][256];       // 32 KB, SWZ16
  __shared__ u16 Hs[64][128];       // 16 KB, SWZ4 (row-major [tok][hid])
  __shared__ u16 Ws[128 * 128];     // 32 KB: ph1 flat [128][128]; ph2 flat [256][64]

  const int tid = threadIdx.x, lane = tid & 63, wn = tid >> 6;   // 8 waves
  const int rsel = lane & 15, ksel = (lane >> 4) * 8;
  const f32x4 zero = {0.f, 0.f, 0.f, 0.f};

  // W1 half-tile [128][128] = 2048 chunks -> 4/thread (row tid>>2, 32-col group)
  const int w1r = tid >> 2, w1cb = (tid & 3) * 32;
  // W2 tile [256][64] = 2048 chunks -> 4/thread
  const int w2r = tid >> 1, w2c = 32 * (tid & 1);

  // preload W1 hc=0 stage0, then stage X (gathered, swizzled)
  short8 a0 = *(const short8*)(W1 + (size_t)w1r * 256 + w1cb);
  short8 a1 = *(const short8*)(W1 + (size_t)w1r * 256 + w1cb + 8);
  short8 a2 = *(const short8*)(W1 + (size_t)w1r * 256 + w1cb + 16);
  short8 a3 = *(const short8*)(W1 + (size_t)w1r * 256 + w1cb + 24);
  for (int ch = tid; ch < 2048; ch += 512) {
    int r = ch >> 5, c = (ch & 31) * 8;
    int arr = gidx[min(row0 + r, Meff - 1)];
    *(short8*)&Xs[r][SWZ(r, c)] = *(const short8*)(x1h + (size_t)arr * 256 + c);
  }

  f32x4 acc2[2][4];                 // [out-tile][tok-tile]
#pragma unroll
  for (int i = 0; i < 2; ++i)
#pragma unroll
    for (int j = 0; j < 4; ++j) acc2[i][j] = zero;

  f32x4 acc1[4];                    // [tok-tile]

  // ph1 stage st (0/1): A = W1 rows (hid, Ws[128][128]), B = X token tiles
  auto ph1 = [&](int st) {
    __builtin_amdgcn_s_setprio(1);
#pragma unroll
    for (int kk = 0; kk < 4; ++kk) {
      int wrow = wn * 16 + rsel;
      int wc = kk * 32 + ksel;
      short8 wf = *(const short8*)&Ws[wrow * 128 + SWZ(wrow, wc)];
      int kglob = st * 128 + kk * 32 + ksel;
#pragma unroll
      for (int tt = 0; tt < 4; ++tt) {
        int xrow = tt * 16 + rsel;
        short8 xf = *(const short8*)&Xs[xrow][SWZ(xrow, kglob)];
        acc1[tt] = __builtin_amdgcn_mfma_f32_16x16x32_bf16(wf, xf, acc1[tt], 0, 0, 0);
      }
    }
    __builtin_amdgcn_s_setprio(0);
  };
  // ph2 half st (0/1): A = W2 rows (out, Ws[256][64]), B = H token tiles
  auto ph2 = [&](int st) {
    __builtin_amdgcn_s_setprio(1);
#pragma unroll
    for (int kk = 0; kk < 2; ++kk) {
      int wc = kk * 32 + ksel;
      short8 wf[2];
#pragma unroll
      for (int ot = 0; ot < 2; ++ot) {
        int wrow = wn * 32 + ot * 16 + rsel;
        wf[ot] = *(const short8*)&Ws[wrow * 64 + SWZ(wrow, wc)];
      }
      int kc = st * 64 + kk * 32 + ksel;
#pragma unroll
      for (int tt = 0; tt < 4; ++tt) {
        int tok = tt * 16 + rsel;
        short4v lo = *(const short4v*)&Hs[tok][SWZ4(tok, kc)];
        short4v hi = *(const short4v*)&Hs[tok][SWZ4(tok, kc + 4)];
        short8 hf = {lo[0], lo[1], lo[2], lo[3], hi[0], hi[1], hi[2], hi[3]};
#pragma unroll
        for (int ot = 0; ot < 2; ++ot)
          acc2[ot][tt] = __builtin_amdgcn_mfma_f32_16x16x32_bf16(wf[ot], hf, acc2[ot][tt], 0, 0, 0);
      }
    }
    __builtin_amdgcn_s_setprio(0);
  };

  for (int hc = 0; hc < 8; ++hc) {
    const u16* W1c = W1 + (size_t)hc * 128 * 256;
    const u16* W2c = W2 + hc * 128;

    // stage W1 half0 (a regs) into Ws[128][128]
    *(short8*)&Ws[w1r * 128 + SWZ(w1r, w1cb)] = a0;
    *(short8*)&Ws[w1r * 128 + SWZ(w1r, w1cb + 8)] = a1;
    *(short8*)&Ws[w1r * 128 + SWZ(w1r, w1cb + 16)] = a2;
    *(short8*)&Ws[w1r * 128 + SWZ(w1r, w1cb + 24)] = a3;
    // issue W1 half1
    short8 b0 = *(const short8*)(W1c + (size_t)w1r * 256 + 128 + w1cb);
    short8 b1 = *(const short8*)(W1c + (size_t)w1r * 256 + 128 + w1cb + 8);
    short8 b2 = *(const short8*)(W1c + (size_t)w1r * 256 + 128 + w1cb + 16);
    short8 b3 = *(const short8*)(W1c + (size_t)w1r * 256 + 128 + w1cb + 24);
    __syncthreads();                                           // B1
#pragma unroll
    for (int i = 0; i < 4; ++i) acc1[i] = zero;
    ph1(0);                                                    // K 0..127
    __syncthreads();                                           // B2 (reads done)
    *(short8*)&Ws[w1r * 128 + SWZ(w1r, w1cb)] = b0;
    *(short8*)&Ws[w1r * 128 + SWZ(w1r, w1cb + 8)] = b1;
    *(short8*)&Ws[w1r * 128 + SWZ(w1r, w1cb + 16)] = b2;
    *(short8*)&Ws[w1r * 128 + SWZ(w1r, w1cb + 24)] = b3;
    // issue W2 half0
    short8 q0 = *(const short8*)(W2c + (size_t)w2r * 1024 + w2c);
    short8 q1 = *(const short8*)(W2c + (size_t)w2r * 1024 + w2c + 8);
    short8 q2 = *(const short8*)(W2c + (size_t)w2r * 1024 + w2c + 16);
    short8 q3 = *(const short8*)(W2c + (size_t)w2r * 1024 + w2c + 24);
    __syncthreads();                                           // B3
    ph1(1);                                                    // K 128..255

    // ---- gelu -> Hs (packed ushort4, SWZ4) ----
#pragma unroll
    for (int tt = 0; tt < 4; ++tt) {
      int tok = tt * 16 + rsel;
      int hid0 = wn * 16 + (lane >> 4) * 4;
      u16 hv[4];
#pragma unroll
      for (int r = 0; r < 4; ++r) {
        float v = acc1[tt][r] + B1[hc * 128 + hid0 + r];
        float u = 1.5957691216057308f * (v + 0.044715f * v * v * v);
        hv[r] = bfbits(v / (1.f + __expf(-u)));
      }
      *(ushort4*)&Hs[tok][SWZ4(tok, hid0)] = make_ushort4(hv[0], hv[1], hv[2], hv[3]);
    }
    __syncthreads();                                           // B4 (Hs ready, Ws free)

    // ---- phase 2: 2 halves of BK=64, Ws as [256][64] ----
    *(short8*)&Ws[w2r * 64 + SWZ(w2r, w2c)] = q0;
    *(short8*)&Ws[w2r * 64 + SWZ(w2r, w2c + 8)] = q1;
    *(short8*)&Ws[w2r * 64 + SWZ(w2r, w2c + 16)] = q2;
    *(short8*)&Ws[w2r * 64 + SWZ(w2r, w2c + 24)] = q3;
    q0 = *(const short8*)(W2c + (size_t)w2r * 1024 + 64 + w2c);
    q1 = *(const short8*)(W2c + (size_t)w2r * 1024 + 64 + w2c + 8);
    q2 = *(const short8*)(W2c + (size_t)w2r * 1024 + 64 + w2c + 16);
    q3 = *(const short8*)(W2c + (size_t)w2r * 1024 + 64 + w2c + 24);
    __syncthreads();                                           // B5
    ph2(0);
    __syncthreads();                                           // B6
    *(short8*)&Ws[w2r * 64 + SWZ(w2r, w2c)] = q0;
    *(short8*)&Ws[w2r * 64 + SWZ(w2r, w2c + 8)] = q1;
    *(short8*)&Ws[w2r * 64 + SWZ(w2r, w2c + 16)] = q2;
    *(short8*)&Ws[w2r * 64 + SWZ(w2r, w2c + 24)] = q3;
    if (hc < 7) {   // next-hc W1 half0 loads hide under ph2 half1
      const u16* W1n = W1 + (size_t)(hc + 1) * 128 * 256;
      a0 = *(const short8*)(W1n + (size_t)w1r * 256 + w1cb);
      a1 = *(const short8*)(W1n + (size_t)w1r * 256 + w1cb + 8);
      a2 = *(const short8*)(W1n + (size_t)w1r * 256 + w1cb + 16);
      a3 = *(const short8*)(W1n + (size_t)w1r * 256 + w1cb + 24);
    }
    __syncthreads();                                           // B7
    ph2(1);
    __syncthreads();                                           // B8
  }

  // ---- epilogue: yslot = gate * (Y + b2), float4 stores ----
#pragma unroll
  for (int tt = 0; tt < 4; ++tt) {
    int grow = row0 + tt * 16 + rsel;
    if (grow < Meff) {
      int tk = gidx[grow];
      float gt = gates[(size_t)tk * 6 + e];
#pragma unroll
      for (int ot = 0; ot < 2; ++ot) {
        int out0 = wn * 32 + ot * 16 + (lane >> 4) * 4;
        float4 w4 = make_float4(gt * (acc2[ot][tt][0] + B2[out0]),
                                gt * (acc2[ot][tt][1] + B2[out0 + 1]),
                                gt * (acc2[ot][tt][2] + B2[out0 + 2]),
                                gt * (acc2[ot][tt][3] + B2[out0 + 3]));
        *(float4*)&yslot[(size_t)(hbase + grow) * 256 + out0] = w4;
      }
    }
  }
}

// ---------------------------------------------------------------------------
// LayerNorm over E=256: wave per token; bf16 out
// ---------------------------------------------------------------------------
__global__ __launch_bounds__(256) void ln_kernel(const float* __restrict__ in,
    const float* __restrict__ g, const float* __restrict__ b, u16* __restrict__ oh)
{
  const int lane = threadIdx.x & 63;
  const int t = blockIdx.x * 4 + (threadIdx.x >> 6);
  const float4 v = *(const float4*)(in + (size_t)t * 256 + lane * 4);
  float s = v.x + v.y + v.z + v.w;
  float sq = v.x * v.x + v.y * v.y + v.z * v.z + v.w * v.w;
#pragma unroll
  for (int o = 32; o >= 1; o >>= 1) {
    s  += __shfl_xor(s,  o, 64);
    sq += __shfl_xor(sq, o, 64);
  }
  float mu = s * (1.f / 256.f);
  float var = sq * (1.f / 256.f) - mu * mu;
  float rstd = rsqrtf(var + 1e-5f);
  const float4 gv = *(const float4*)(g + lane * 4);
  const float4 bv = *(const float4*)(b + lane * 4);
  *(ushort4*)(oh + (size_t)t * 256 + lane * 4) = make_ushort4(
      bfbits((v.x - mu) * rstd * gv.x + bv.x), bfbits((v.y - mu) * rstd * gv.y + bv.y),
      bfbits((v.z - mu) * rstd * gv.z + bv.z), bfbits((v.w - mu) * rstd * gv.w + bv.w));
}

// ---------------------------------------------------------------------------
// Fused slot-combine + LayerNorm: moe[t] = yslot[s0]+yslot[s1]; x2 = LN(moe)
// ---------------------------------------------------------------------------
__global__ __launch_bounds__(256) void ln2_combine(const float* __restrict__ yslot,
    const int* __restrict__ invslot,
    const float* __restrict__ g, const float* __restrict__ b, float* __restrict__ outf)
{
  const int lane = threadIdx.x & 63;
  const int t = blockIdx.x * 4 + (threadIdx.x >> 6);
  const int s0 = invslot[t * 2], s1 = invslot[t * 2 + 1];
  const float4 a = *(const float4*)(yslot + (size_t)s0 * 256 + lane * 4);
  const float4 c = *(const float4*)(yslot + (size_t)s1 * 256 + lane * 4);
  float4 v = make_float4(a.x + c.x, a.y + c.y, a.z + c.z, a.w + c.w);
  float s = v.x + v.y + v.z + v.w;
  float sq = v.x * v.x + v.y * v.y + v.z * v.z + v.w * v.w;
#pragma unroll
  for (int o = 32; o >= 1; o >>= 1) {
    s  += __shfl_xor(s,  o, 64);
    sq += __shfl_xor(sq, o, 64);
  }
  float mu = s * (1.f / 256.f);
  float var = sq * (1.f / 256.f) - mu * mu;
  float rstd = rsqrtf(var + 1e-5f);
  const float4 gv = *(const float4*)(g + lane * 4);
  const float4 bv = *(const float4*)(b + lane * 4);
  *(float4*)(outf + (size_t)t * 256 + lane * 4) = make_float4(
      (v.x - mu) * rstd * gv.x + bv.x, (v.y - mu) * rstd * gv.y + bv.y,
      (v.z - mu) * rstd * gv.z + bv.z, (v.w - mu) * rstd * gv.w + bv.w);
}

// ---------------------------------------------------------------------------
// MFMA attention: one block per (b,h), 4 waves, 13 m-tiles of 16 q-rows.
// ao written split (hi+lo): feeds wo -> x1f -> router (gate precision).
// ---------------------------------------------------------------------------
__global__ __launch_bounds__(256) void attn_mfma(const u16* __restrict__ qkvb,
                                                 u16* __restrict__ aoh, u16* __restrict__ aol) {
  __shared__ u16 Qs[208][40];
  __shared__ u16 Ks[208][40];
  __shared__ u16 Vt[32][256];
  __shared__ u16 Ps[4][16][232];
  const int tid = threadIdx.x, lane = tid & 63, wave = tid >> 6;
  const int b = blockIdx.x >> 3, h = blockIdx.x & 7;
  const size_t base = (size_t)b * 196 * 768 + h * 32;
  const short8 z8 = {0, 0, 0, 0, 0, 0, 0, 0};

  for (int idx = tid; idx < 832; idx += 256) {
    int r = idx >> 2, c = (idx & 3) * 8;
    short8 q = z8, k = z8;
    if (r < 196) {
      q = *(const short8*)(qkvb + base + (size_t)r * 768 + c);
      k = *(const short8*)(qkvb + base + (size_t)r * 768 + 256 + c);
    }
    *(short8*)&Qs[r][c] = q;
    *(short8*)&Ks[r][c] = k;
  }
  for (int idx = tid; idx < 32 * 224; idx += 256) {
    int c = idx & 31, k = idx >> 5;
    u16 v = 0;
    if (k < 196) v = qkvb[base + (size_t)k * 768 + 512 + c];
    Vt[c][k ^ ((c & 7) << 3)] = v;
  }
  {
    int r = lane >> 2, c0 = 208 + (lane & 3) * 4;
    Ps[wave][r][c0] = 0; Ps[wave][r][c0 + 1] = 0; Ps[wave][r][c0 + 2] = 0; Ps[wave][r][c0 + 3] = 0;
  }
  __syncthreads();

  const int rsel = lane & 15, ksel = (lane >> 4) * 8;
  const f32x4 zero = {0.f, 0.f, 0.f, 0.f};

  for (int mt = wave; mt < 13; mt += 4) {
    short8 aq = *(const short8*)&Qs[mt * 16 + rsel][ksel];
    f32x4 sacc[13];
    __builtin_amdgcn_s_setprio(1);
#pragma unroll
    for (int n = 0; n < 13; ++n)
      sacc[n] = __builtin_amdgcn_mfma_f32_16x16x32_bf16(
          aq, *(const short8*)&Ks[n * 16 + rsel][ksel], zero, 0, 0, 0);
    __builtin_amdgcn_s_setprio(0);

#pragma unroll
    for (int r = 0; r < 4; ++r) {
      float mv = -1e30f;
#pragma unroll
      for (int n = 0; n < 13; ++n) {
        float sv = sacc[n][r] * 0.17677669529663687f;
        sacc[n][r] = sv;
        if (n * 16 + rsel < 196) mv = fmaxf(mv, sv);
      }
      mv = fmaxf(mv, __shfl_xor(mv, 1, 64));
      mv = fmaxf(mv, __shfl_xor(mv, 2, 64));
      mv = fmaxf(mv, __shfl_xor(mv, 4, 64));
      mv = fmaxf(mv, __shfl_xor(mv, 8, 64));
      float sm = 0.f;
#pragma unroll
      for (int n = 0; n < 13; ++n) {
        float p = (n * 16 + rsel < 196) ? __expf(sacc[n][r] - mv) : 0.f;
        sacc[n][r] = p;
        sm += p;
      }
      sm += __shfl_xor(sm, 1, 64);
      sm += __shfl_xor(sm, 2, 64);
      sm += __shfl_xor(sm, 4, 64);
      sm += __shfl_xor(sm, 8, 64);
      float inv = 1.f / sm;
      int prow = (lane >> 4) * 4 + r;
#pragma unroll
      for (int n = 0; n < 13; ++n)
        Ps[wave][prow][n * 16 + rsel] = bfbits(sacc[n][r] * inv);
    }

    f32x4 oacc[2] = {zero, zero};
    __builtin_amdgcn_s_setprio(1);
#pragma unroll
    for (int kk = 0; kk < 7; ++kk) {
      short8 ap = *(const short8*)&Ps[wave][rsel][kk * 32 + ksel];
#pragma unroll
      for (int nt = 0; nt < 2; ++nt) {
        int d = nt * 16 + rsel;
        short8 bv = *(const short8*)&Vt[d][(kk * 32 + ksel) ^ ((d & 7) << 3)];
        oacc[nt] = __builtin_amdgcn_mfma_f32_16x16x32_bf16(ap, bv, oacc[nt], 0, 0, 0);
      }
    }
    __builtin_amdgcn_s_setprio(0);
#pragma unroll
    for (int nt = 0; nt < 2; ++nt) {
#pragma unroll
      for (int r = 0; r < 4; ++r) {
        int row = mt * 16 + (lane >> 4) * 4 + r;
        if (row < 196) {
          size_t oi = ((size_t)b * 196 + row) * 256 + h * 32 + nt * 16 + rsel;
          u16 hh, ll; fsplit(oacc[nt][r], hh, ll);
          aoh[oi] = hh; aol[oi] = ll;
        }
      }
    }
  }
}

// ---------------------------------------------------------------------------
// Router: wave per token; 6 logits, softmax, top-2 -> dense gates [T,6]
// ---------------------------------------------------------------------------
__global__ __launch_bounds__(256) void router_kernel(const float* __restrict__ x1,
    const float* __restrict__ rw, const float* __restrict__ rb, float* __restrict__ gates)
{
  const int lane = threadIdx.x & 63;
  const int t = blockIdx.x * 4 + (threadIdx.x >> 6);
  const float4 xv = *(const float4*)(x1 + (size_t)t * 256 + lane * 4);
  float logit[6];
#pragma unroll
  for (int e = 0; e < 6; ++e) {
    const float4 wv = *(const float4*)(rw + e * 256 + lane * 4);
    float p = xv.x * wv.x + xv.y * wv.y + xv.z * wv.z + xv.w * wv.w;
#pragma unroll
    for (int o = 32; o >= 1; o >>= 1) p += __shfl_xor(p, o, 64);
    logit[e] = p + rb[e];
  }
  float mx = logit[0];
#pragma unroll
  for (int e = 1; e < 6; ++e) mx = fmaxf(mx, logit[e]);
  float pe[6], sum = 0.f;
#pragma unroll
  for (int e = 0; e < 6; ++e) { pe[e] = __expf(logit[e] - mx); sum += pe[e]; }
  float inv = 1.f / sum;
  int i1 = 0; float p1 = pe[0];
#pragma unroll
  for (int e = 1; e < 6; ++e) if (pe[e] > p1) { p1 = pe[e]; i1 = e; }
  int i2 = -1; float p2 = -1.f;
#pragma unroll
  for (int e = 0; e < 6; ++e) if (e != i1 && pe[e] > p2) { p2 = pe[e]; i2 = e; }
  if (lane < 6)
    gates[(size_t)t * 6 + lane] = (lane == i1) ? p1 * inv : ((lane == i2) ? p2 * inv : 0.f);
}

// ---------------------------------------------------------------------------
// Scatter: build per-expert token lists (block-aggregated atomics)
// ---------------------------------------------------------------------------
__global__ __launch_bounds__(256) void scatter_kernel(const float* __restrict__ gates,
                                                      int* __restrict__ cnt, int* __restrict__ idx) {
  __shared__ int lcnt[6], lbase[6];
  const int t = blockIdx.x * 256 + threadIdx.x;
  if (threadIdx.x < 6) lcnt[threadIdx.x] = 0;
  __syncthreads();
  float g[6]; int lpos[6];
#pragma unroll
  for (int e = 0; e < 6; ++e) {
    g[e] = gates[(size_t)t * 6 + e];
    if (g[e] > 0.f) lpos[e] = atomicAdd(&lcnt[e], 1);
  }
  __syncthreads();
  if (threadIdx.x < 6) lbase[threadIdx.x] = atomicAdd(&cnt[threadIdx.x], lcnt[threadIdx.x]);
  __syncthreads();
#pragma unroll
  for (int e = 0; e < 6; ++e)
    if (g[e] > 0.f) idx[(size_t)e * T_TOK + lbase[e] + lpos[e]] = t;
}

// exclusive prefix over the 6 expert counts -> segment bases in slot buffer
__global__ void prefix6_kernel(const int* __restrict__ cnt, int* __restrict__ base) {
  if (threadIdx.x == 0) {
    int s = 0;
#pragma unroll
    for (int e = 0; e < 6; ++e) { base[e] = s; s += cnt[e]; }
  }
}

// token -> its 2 slot positions in the concatenated expert segments
__global__ __launch_bounds__(256) void slotmap_kernel(const int* __restrict__ idx,
    const int* __restrict__ cnt, const int* __restrict__ base,
    int* __restrict__ nslot, int* __restrict__ invslot) {
  const int e = blockIdx.y;
  const int p = blockIdx.x * 256 + threadIdx.x;
  if (p < cnt[e]) {
    int t = idx[(size_t)e * T_TOK + p];
    int j = atomicAdd(&nslot[t], 1);
    invslot[(size_t)t * 2 + j] = base[e] + p;
  }
}

// ---------------------------------------------------------------------------
// Mean-pool over tokens, then classifier head (fp32)
// ---------------------------------------------------------------------------
__global__ __launch_bounds__(256) void pool_kernel(const float* __restrict__ x2, float* __restrict__ pooled) {
  int b = blockIdx.x, e = threadIdx.x;
  float s = 0.f;
  for (int n = 0; n < 196; ++n) s += x2[((size_t)b * 196 + n) * 256 + e];
  pooled[(size_t)b * 256 + e] = s * (1.f / 196.f);
}

__global__ __launch_bounds__(256) void head_kernel(const float* __restrict__ pooled,
    const float* __restrict__ hw, const float* __restrict__ hb, float* __restrict__ out) {
  __shared__ float p[256];
  int b = blockIdx.x;
  p[threadIdx.x] = pooled[(size_t)b * 256 + threadIdx.x];
  __syncthreads();
  for (int cls = threadIdx.x; cls < 1000; cls += 256) {
    const float* w = hw + (size_t)cls * 256;
    float s = hb[cls];
    for (int k = 0; k < 256; k += 4)
      s += p[k] * w[k] + p[k + 1] * w[k + 1] + p[k + 2] * w[k + 2] + p[k + 3] * w[k + 3];
    out[(size_t)b * 1000 + cls] = s;
  }
}

// ---------------------------------------------------------------------------
// Weight prep: f32 -> hi/lo bf16 split; transpose+cast (hi-only) for MoE
// ---------------------------------------------------------------------------
__global__ void cast_split_kernel(const float* __restrict__ in,
                                  u16* __restrict__ oh, u16* __restrict__ ol, int n4) {
  int id = blockIdx.x * 256 + threadIdx.x;
  if (id >= n4) return;
  float4 v = ((const float4*)in)[id];
  u16 h0, l0, h1, l1, h2, l2, h3, l3;
  fsplit(v.x, h0, l0); fsplit(v.y, h1, l1); fsplit(v.z, h2, l2); fsplit(v.w, h3, l3);
  ((ushort4*)oh)[id] = make_ushort4(h0, h1, h2, h3);
  ((ushort4*)ol)[id] = make_ushort4(l0, l1, l2, l3);
}

__global__ __launch_bounds__(256) void transpose_cast(const float* __restrict__ in,
    u16* __restrict__ oh, int R, int C) {
  __shared__ float tile[32][33];
  const int e = blockIdx.z;
  const int bc = blockIdx.x * 32, br = blockIdx.y * 32;
  const int tx = threadIdx.x & 31, ty = threadIdx.x >> 5;
  const float* src = in + (size_t)e * R * C;
#pragma unroll
  for (int i = 0; i < 32; i += 8)
    tile[ty + i][tx] = src[(size_t)(br + ty + i) * C + bc + tx];
  __syncthreads();
#pragma unroll
  for (int i = 0; i < 32; i += 8) {
    size_t di = (size_t)e * R * C + (size_t)(bc + ty + i) * R + br + tx;
    oh[di] = bfbits(tile[tx][ty + i]);
  }
}

// ---------------------------------------------------------------------------
extern "C" void kernel_launch(void* const* d_in, const int* in_sizes, int n_in,
                              void* d_out, int out_size, void* d_ws, size_t ws_size,
                              hipStream_t stream) {
  (void)in_sizes; (void)n_in; (void)out_size; (void)ws_size;
  const float* x      = (const float*)d_in[0];
  const float* conv_w = (const float*)d_in[1];
  const float* conv_b = (const float*)d_in[2];
  const float* pos    = (const float*)d_in[3];
  const float* ln1_g  = (const float*)d_in[4];
  const float* ln1_b  = (const float*)d_in[5];
  const float* wqkv   = (const float*)d_in[6];
  const float* bqkv   = (const float*)d_in[7];
  const float* wo     = (const float*)d_in[8];
  const float* bo     = (const float*)d_in[9];
  const float* rw     = (const float*)d_in[10];
  const float* rb     = (const float*)d_in[11];
  const float* w1     = (const float*)d_in[12];
  const float* b1     = (const float*)d_in[13];
  const float* w2     = (const float*)d_in[14];
  const float* b2     = (const float*)d_in[15];
  const float* ln2_g  = (const float*)d_in[16];
  const float* ln2_b  = (const float*)d_in[17];
  const float* hw     = (const float*)d_in[18];
  const float* hb     = (const float*)d_in[19];
  float* out = (float*)d_out;

  const int T = T_TOK;
  char* ws = (char*)d_ws;
  size_t off = 0;
  auto alloc = [&](size_t bytes) -> void* {
    void* p = ws + off;
    off += (bytes + 255) & ~(size_t)255;
    return p;
  };
  // region 0: tok+xnh+qkvb -> reused as x2 after qkv consumed
  float* tok    = (float*)alloc((size_t)T * 256 * 4);
  u16*   xnh    = (u16*)  alloc((size_t)T * 256 * 2);
  u16*   qkvb   = (u16*)  alloc((size_t)T * 768 * 2);
  // region 1: aoh+aol+x1f == exactly [2T,256] f32 -> reused as yslot
  u16*   aoh    = (u16*)  alloc((size_t)T * 256 * 2);
  u16*   aol    = (u16*)  alloc((size_t)T * 256 * 2);
  float* x1f    = (float*)alloc((size_t)T * 256 * 4);
  u16*   x1h    = (u16*)  alloc((size_t)T * 256 * 2);
  float* gates  = (float*)alloc((size_t)T * 6 * 4);
  int*   idx    = (int*)  alloc((size_t)6 * T * 4);
  int*   cnt    = (int*)  alloc(256);
  int*   base   = (int*)  alloc(256);
  int*   nslot  = (int*)  alloc((size_t)T * 4);
  int*   invslot= (int*)  alloc((size_t)2 * T * 4);
  float* pooled = (float*)alloc((size_t)128 * 256 * 4);
  u16*   cwh    = (u16*)  alloc((size_t)196608 * 2);
  u16*   cwl    = (u16*)  alloc((size_t)196608 * 2);
  u16*   wqh    = (u16*)  alloc((size_t)196608 * 2);
  u16*   wql    = (u16*)  alloc((size_t)196608 * 2);
  u16*   woh    = (u16*)  alloc((size_t)65536 * 2);
  u16*   wol    = (u16*)  alloc((size_t)65536 * 2);
  u16*   w1th   = (u16*)  alloc((size_t)6 * 262144 * 2);
  u16*   w2th   = (u16*)  alloc((size_t)6 * 262144 * 2);
  // aliases (lifetimes disjoint):
  float* yslot = (float*)aoh;   // [2T,256] f32 (region 1; exact fit)
  float* x2    = (float*)ws;    // [T,256] f32 (region 0 head; tok dead by then)

  // --- weight prep (router-path weights hi+lo; MoE weights hi-only) ---
  cast_split_kernel<<<192, 256, 0, stream>>>(conv_w, cwh, cwl, 49152);
  cast_split_kernel<<<192, 256, 0, stream>>>(wqkv, wqh, wql, 49152);
  cast_split_kernel<<<64, 256, 0, stream>>>(wo, woh, wol, 16384);
  transpose_cast<<<dim3(32, 8, 6), 256, 0, stream>>>(w1, w1th, 256, 1024);  // [e][n][k]
  transpose_cast<<<dim3(8, 32, 6), 256, 0, stream>>>(w2, w2th, 1024, 256);  // [e][n][k]

  // --- patch embedding (fused im2col + split-A GEMM) ---
  gemm_patch<<<dim3(196, 2), 256, 0, stream>>>(x, cwh, cwl, conv_b, pos, tok);

  // --- attention block ---
  ln_kernel<<<6272, 256, 0, stream>>>(tok, ln1_g, ln1_b, xnh);
  gemm_bs<5, false><<<dim3(196, 6), 256, 0, stream>>>(xnh, nullptr, wqh, wql, T, 768, 256,
      bqkv, nullptr, nullptr, qkvb);
  attn_mfma<<<1024, 256, 0, stream>>>(qkvb, aoh, aol);
  gemm_bs<2, true><<<dim3(196, 2), 256, 0, stream>>>(aoh, aol, woh, wol, T, 256, 256,
      bo, tok, x1f, x1h);

  // --- MoE (top-2 sparse, fused GEMM1+gelu+GEMM2, 2 blocks/CU) ---
  router_kernel<<<6272, 256, 0, stream>>>(x1f, rw, rb, gates);
  hipMemsetAsync(cnt, 0, 256, stream);
  scatter_kernel<<<98, 256, 0, stream>>>(gates, cnt, idx);
  prefix6_kernel<<<1, 64, 0, stream>>>(cnt, base);
  hipMemsetAsync(nslot, 0, (size_t)T * 4, stream);
  slotmap_kernel<<<dim3(98, 6), 256, 0, stream>>>(idx, cnt, base, nslot, invslot);
  moe_fused<<<dim3(392, 1, 6), 512, 0, stream>>>(x1h, w1th, w2th,
      b1, b2, gates, idx, cnt, base, yslot);

  // --- final norm (fused slot combine), pool, head ---
  ln2_combine<<<6272, 256, 0, stream>>>(yslot, invslot, ln2_g, ln2_b, x2);
  pool_kernel<<<128, 256, 0, stream>>>(x2, pooled);
  head_kernel<<<128, 256, 0, stream>>>(pooled, hw, hb, out);
}

// Round 15
// 392.338 us; speedup vs baseline: 1.0321x; 1.0321x over previous
//
#include <hip/hip_runtime.h>
#include <hip/hip_bf16.h>

typedef unsigned short u16;
typedef short short8 __attribute__((ext_vector_type(8)));
typedef short short4v __attribute__((ext_vector_type(4)));
typedef float f32x4 __attribute__((ext_vector_type(4)));

#define T_TOK 25088   // 128*196
#define NTOK 196
// 16B-chunk XOR swizzle (T2-style)
#define SWZ(r, c) ((((((c) >> 3) ^ ((r) & 7)) << 3)) | ((c) & 7))
// 8B-chunk XOR swizzle (for Hs: packed ushort4 writes + paired b64 reads)
#define SWZ4(r, c) ((((((c) >> 2) & 16) | ((((c) >> 2) ^ (r)) & 15)) << 2) | ((c) & 3))

__device__ __forceinline__ u16 bfbits(float v) {
  __hip_bfloat16 h = __float2bfloat16(v);
  return *reinterpret_cast<u16*>(&h);
}
__device__ __forceinline__ float b2f(u16 u) {
  __hip_bfloat16 h = *reinterpret_cast<__hip_bfloat16*>(&u);
  return __bfloat162float(h);
}
// near-fp32 as hi+lo bf16 pair (Ootomo split)
__device__ __forceinline__ void fsplit(float v, u16& hi, u16& lo) {
  hi = bfbits(v);
  lo = bfbits(v - b2f(hi));
}

// ---------------------------------------------------------------------------
// Dense GEMM (r9/r11): C[M,N] = A[M,K] @ (Bh+Bl)[N,K]^T + bias.
// A split (3 MFMA/frag) when SPLITA — router-input path (wo).
// 128x128 tile, BK=32, 256 threads (4 waves 2x2), reg-staged 1-deep prefetch.
// EPI: 2 +resid->f32+bf16 | 5 ->bf16
// ---------------------------------------------------------------------------
template<int EPI, bool SPLITA>
__global__ __launch_bounds__(256) void gemm_bs(
    const u16* __restrict__ A, const u16* __restrict__ Al,
    const u16* __restrict__ Bh, const u16* __restrict__ Bl,
    int M, int N, int K,
    const float* __restrict__ bias, const float* __restrict__ extra,
    float* __restrict__ outf, u16* __restrict__ obh)
{
  __shared__ u16 As[128][40];                      // +8 pad: 2-way banks
  __shared__ u16 Asl[SPLITA ? 128 : 1][40];
  __shared__ u16 Bsh[128][40], Bsl[128][40];
  const int tid = threadIdx.x;
  const int lane = tid & 63, wave = tid >> 6;
  const int wm = wave >> 1, wn = wave & 1;
  const int row0 = blockIdx.x * 128, col0 = blockIdx.y * 128;

  const int r0 = tid >> 2, r1 = r0 + 64, co = (tid & 3) * 8;
  const int ar0 = row0 + r0, ar1 = row0 + r1;

  f32x4 acc[4][4];
  const f32x4 zero = {0.f, 0.f, 0.f, 0.f};
#pragma unroll
  for (int i = 0; i < 4; ++i)
#pragma unroll
    for (int j = 0; j < 4; ++j) acc[i][j] = zero;

  const int rsel = lane & 15, ksel = (lane >> 4) * 8;

  short8 ra, rl, rb0, rb1, rc0, rc1;
  auto issue = [&](int k0) {
    ra = *(const short8*)(A + (size_t)ar0 * K + k0 + co);
    rl = *(const short8*)(A + (size_t)ar1 * K + k0 + co);
    rb0 = *(const short8*)(Bh + (size_t)(col0 + r0) * K + k0 + co);
    rb1 = *(const short8*)(Bh + (size_t)(col0 + r1) * K + k0 + co);
    rc0 = *(const short8*)(Bl + (size_t)(col0 + r0) * K + k0 + co);
    rc1 = *(const short8*)(Bl + (size_t)(col0 + r1) * K + k0 + co);
  };
  short8 sa, sl;
  auto issueS = [&](int k0) {
    if constexpr (SPLITA) {
      sa = *(const short8*)(Al + (size_t)ar0 * K + k0 + co);
      sl = *(const short8*)(Al + (size_t)ar1 * K + k0 + co);
    }
  };
  auto commit = [&]() {
    *(short8*)&As[r0][co] = ra;
    *(short8*)&As[r1][co] = rl;
    if constexpr (SPLITA) {
      *(short8*)&Asl[r0][co] = sa;
      *(short8*)&Asl[r1][co] = sl;
    }
    *(short8*)&Bsh[r0][co] = rb0;
    *(short8*)&Bsh[r1][co] = rb1;
    *(short8*)&Bsl[r0][co] = rc0;
    *(short8*)&Bsl[r1][co] = rc1;
  };

  issue(0);
  issueS(0);
  commit();
  __syncthreads();

  for (int k0 = 0;;) {
    const bool more = (k0 + 32 < K);
    if (more) { issue(k0 + 32); issueS(k0 + 32); }
    short8 af[4], al4[4], bh4[4], bl4[4];
#pragma unroll
    for (int i = 0; i < 4; ++i) {
      af[i] = *(const short8*)&As[wm * 64 + i * 16 + rsel][ksel];
      if constexpr (SPLITA) al4[i] = *(const short8*)&Asl[wm * 64 + i * 16 + rsel][ksel];
    }
#pragma unroll
    for (int j = 0; j < 4; ++j) {
      bh4[j] = *(const short8*)&Bsh[wn * 64 + j * 16 + rsel][ksel];
      bl4[j] = *(const short8*)&Bsl[wn * 64 + j * 16 + rsel][ksel];
    }
#pragma unroll
    for (int i = 0; i < 4; ++i)
#pragma unroll
      for (int j = 0; j < 4; ++j) {
        acc[i][j] = __builtin_amdgcn_mfma_f32_16x16x32_bf16(af[i], bh4[j], acc[i][j], 0, 0, 0);
        if constexpr (SPLITA)
          acc[i][j] = __builtin_amdgcn_mfma_f32_16x16x32_bf16(al4[i], bh4[j], acc[i][j], 0, 0, 0);
        acc[i][j] = __builtin_amdgcn_mfma_f32_16x16x32_bf16(af[i], bl4[j], acc[i][j], 0, 0, 0);
      }
    k0 += 32;
    if (!more) break;
    __syncthreads();
    commit();
    __syncthreads();
  }

#pragma unroll
  for (int i = 0; i < 4; ++i) {
#pragma unroll
    for (int j = 0; j < 4; ++j) {
#pragma unroll
      for (int r = 0; r < 4; ++r) {
        int grow = row0 + wm * 64 + i * 16 + (lane >> 4) * 4 + r;   // token
        int gcol = col0 + wn * 64 + j * 16 + rsel;                  // feature
        float v = acc[i][j][r] + bias[gcol];
        size_t oi = (size_t)grow * N + gcol;
        if constexpr (EPI == 2) {
          v += extra[oi];                                  // residual
          outf[oi] = v;
          obh[oi] = bfbits(v);
        } else if constexpr (EPI == 5) {
          obh[oi] = bfbits(v);
        }
      }
    }
  }
}

// ---------------------------------------------------------------------------
// Patch-embed GEMM with FUSED im2col: C[T,256] = A[T,768] @ convW^T + b + pos,
// where A rows are computed from x[B,3,224,224] on the fly (hi/lo split in
// LDS). k = c*256 + p*16 + q; a BK=32 step = one channel c, rows p, p+1.
// ---------------------------------------------------------------------------
__global__ __launch_bounds__(256) void gemm_patch(
    const float* __restrict__ xin,
    const u16* __restrict__ Bh, const u16* __restrict__ Bl,
    const float* __restrict__ bias, const float* __restrict__ pos,
    float* __restrict__ outf)
{
  __shared__ u16 As[128][40], Asl[128][40];
  __shared__ u16 Bsh[128][40], Bsl[128][40];
  const int tid = threadIdx.x;
  const int lane = tid & 63, wave = tid >> 6;
  const int wm = wave >> 1, wn = wave & 1;
  const int row0 = blockIdx.x * 128, col0 = blockIdx.y * 128;
  const int rsel = lane & 15, ksel = (lane >> 4) * 8;
  const int K = 768, N = 256;

  const int ar = tid >> 1, ph = tid & 1;
  const float* srcbase;
  {
    int t = row0 + ar;
    int b = t / 196, n = t - b * 196;
    int gh = n / 14, gw = n - gh * 14;
    srcbase = xin + ((size_t)(b * 3) * 224 + gh * 16) * 224 + gw * 16;
  }
  const int br0 = tid >> 2, br1 = br0 + 64, bco = (tid & 3) * 8;

  f32x4 acc[4][4];
  const f32x4 zero = {0.f, 0.f, 0.f, 0.f};
#pragma unroll
  for (int i = 0; i < 4; ++i)
#pragma unroll
    for (int j = 0; j < 4; ++j) acc[i][j] = zero;

  float4 fa0, fa1, fa2, fa3;           // A prefetch (16 floats)
  short8 rb0, rb1, rc0, rc1;           // B prefetch
  auto issue = [&](int k0) {
    int c = k0 >> 8, p = ((k0 >> 4) & 15) + ph;
    const float* s = srcbase + ((size_t)c * 224 + p) * 224;
    fa0 = *(const float4*)(s);
    fa1 = *(const float4*)(s + 4);
    fa2 = *(const float4*)(s + 8);
    fa3 = *(const float4*)(s + 12);
    rb0 = *(const short8*)(Bh + (size_t)(col0 + br0) * K + k0 + bco);
    rb1 = *(const short8*)(Bh + (size_t)(col0 + br1) * K + k0 + bco);
    rc0 = *(const short8*)(Bl + (size_t)(col0 + br0) * K + k0 + bco);
    rc1 = *(const short8*)(Bl + (size_t)(col0 + br1) * K + k0 + bco);
  };
  auto commit = [&]() {
    float f[16] = {fa0.x, fa0.y, fa0.z, fa0.w, fa1.x, fa1.y, fa1.z, fa1.w,
                   fa2.x, fa2.y, fa2.z, fa2.w, fa3.x, fa3.y, fa3.z, fa3.w};
    u16 hv[16], lv[16];
#pragma unroll
    for (int j = 0; j < 16; ++j) fsplit(f[j], hv[j], lv[j]);
    short8 h0 = {(short)hv[0], (short)hv[1], (short)hv[2], (short)hv[3],
                 (short)hv[4], (short)hv[5], (short)hv[6], (short)hv[7]};
    short8 h1 = {(short)hv[8], (short)hv[9], (short)hv[10], (short)hv[11],
                 (short)hv[12], (short)hv[13], (short)hv[14], (short)hv[15]};
    short8 l0 = {(short)lv[0], (short)lv[1], (short)lv[2], (short)lv[3],
                 (short)lv[4], (short)lv[5], (short)lv[6], (short)lv[7]};
    short8 l1 = {(short)lv[8], (short)lv[9], (short)lv[10], (short)lv[11],
                 (short)lv[12], (short)lv[13], (short)lv[14], (short)lv[15]};
    *(short8*)&As[ar][ph * 16] = h0;
    *(short8*)&As[ar][ph * 16 + 8] = h1;
    *(short8*)&Asl[ar][ph * 16] = l0;
    *(short8*)&Asl[ar][ph * 16 + 8] = l1;
    *(short8*)&Bsh[br0][bco] = rb0;
    *(short8*)&Bsh[br1][bco] = rb1;
    *(short8*)&Bsl[br0][bco] = rc0;
    *(short8*)&Bsl[br1][bco] = rc1;
  };

  issue(0);
  commit();
  __syncthreads();

  for (int k0 = 0;;) {
    const bool more = (k0 + 32 < K);
    if (more) issue(k0 + 32);
    short8 af[4], al4[4], bh4[4], bl4[4];
#pragma unroll
    for (int i = 0; i < 4; ++i) {
      af[i] = *(const short8*)&As[wm * 64 + i * 16 + rsel][ksel];
      al4[i] = *(const short8*)&Asl[wm * 64 + i * 16 + rsel][ksel];
    }
#pragma unroll
    for (int j = 0; j < 4; ++j) {
      bh4[j] = *(const short8*)&Bsh[wn * 64 + j * 16 + rsel][ksel];
      bl4[j] = *(const short8*)&Bsl[wn * 64 + j * 16 + rsel][ksel];
    }
#pragma unroll
    for (int i = 0; i < 4; ++i)
#pragma unroll
      for (int j = 0; j < 4; ++j) {
        acc[i][j] = __builtin_amdgcn_mfma_f32_16x16x32_bf16(af[i], bh4[j], acc[i][j], 0, 0, 0);
        acc[i][j] = __builtin_amdgcn_mfma_f32_16x16x32_bf16(al4[i], bh4[j], acc[i][j], 0, 0, 0);
        acc[i][j] = __builtin_amdgcn_mfma_f32_16x16x32_bf16(af[i], bl4[j], acc[i][j], 0, 0, 0);
      }
    k0 += 32;
    if (!more) break;
    __syncthreads();
    commit();
    __syncthreads();
  }

#pragma unroll
  for (int i = 0; i < 4; ++i) {
#pragma unroll
    for (int j = 0; j < 4; ++j) {
#pragma unroll
      for (int r = 0; r < 4; ++r) {
        int grow = row0 + wm * 64 + i * 16 + (lane >> 4) * 4 + r;   // token
        int gcol = col0 + wn * 64 + j * 16 + rsel;                  // feature
        float v = acc[i][j][r] + bias[gcol] + pos[(size_t)(grow % NTOK) * N + gcol];
        outf[(size_t)grow * N + gcol] = v;
      }
    }
  }
}

// ---------------------------------------------------------------------------
// Fused MoE v4 (r11/r12): 64-token tiles, hi-only weights, 80 KB LDS,
// 2 blocks/CU, operand-swapped MFMAs (lane holds consecutive hid/out per tok).
// ---------------------------------------------------------------------------
__global__ __launch_bounds__(512, 4) void moe_fused(
    const u16* __restrict__ x1h,
    const u16* __restrict__ w1, const u16* __restrict__ w2,
    const float* __restrict__ b1, const float* __restrict__ b2,
    const float* __restrict__ gates,
    const int* __restrict__ idx_all, const int* __restrict__ cnt_all,
    const int* __restrict__ base_all,
    float* __restrict__ yslot)
{
  const int e = blockIdx.z;
  const int Meff = cnt_all[e];
  const int row0 = blockIdx.x * 64;
  if (row0 >= Meff) return;
  const int* gidx = idx_all + (size_t)e * T_TOK;
  const int hbase = base_all[e];
  const u16* W1 = w1 + (size_t)e * 262144;   // [1024][256] (n,k)
  const u16* W2 = w2 + (size_t)e * 262144;   // [256][1024] (n,k)
  const float* B1 = b1 + e * 1024;
  const float* B2 = b2 + e * 256;

  __shared__ u16 Xs[64][256];       // 32 KB, SWZ16
  __shared__ u16 Hs[64][128];       // 16 KB, SWZ4 (row-major [tok][hid])
  __shared__ u16 Ws[2 * 128 * 64];  // 32 KB: ph1 dbuf 2x[128][64]; ph2 flat [256][64]

  const int tid = threadIdx.x, lane = tid & 63, wn = tid >> 6;   // 8 waves
  const int rsel = lane & 15, ksel = (lane >> 4) * 8;
  const f32x4 zero = {0.f, 0.f, 0.f, 0.f};

  const int w1r = tid >> 2, w1c = ((2 * tid) & 7) * 8;
  const int w2r = tid >> 1, w2c = ((4 * tid) & 7) * 8;

  short8 w1a = *(const short8*)(W1 + (size_t)w1r * 256 + w1c);
  short8 w1b = *(const short8*)(W1 + (size_t)w1r * 256 + w1c + 8);
  for (int ch = tid; ch < 2048; ch += 512) {
    int r = ch >> 5, c = (ch & 31) * 8;
    int arr = gidx[min(row0 + r, Meff - 1)];
    *(short8*)&Xs[r][SWZ(r, c)] = *(const short8*)(x1h + (size_t)arr * 256 + c);
  }

  f32x4 acc2[2][4];                 // [out-tile][tok-tile]
#pragma unroll
  for (int i = 0; i < 2; ++i)
#pragma unroll
    for (int j = 0; j < 4; ++j) acc2[i][j] = zero;

  f32x4 acc1[4];                    // [tok-tile]

  // ph1 step: A = W1 slab rows (hid), B = X token tiles. st = k-stage (0..3)
  auto ph1 = [&](int st, int buf) {
#pragma unroll
    for (int kk = 0; kk < 2; ++kk) {
      int wrow = wn * 16 + rsel;
      int wc = kk * 32 + ksel;
      short8 wf = *(const short8*)&Ws[buf * 8192 + wrow * 64 + SWZ(wrow, wc)];
      int kglob = st * 64 + kk * 32 + ksel;
#pragma unroll
      for (int tt = 0; tt < 4; ++tt) {
        int xrow = tt * 16 + rsel;
        short8 xf = *(const short8*)&Xs[xrow][SWZ(xrow, kglob)];
        acc1[tt] = __builtin_amdgcn_mfma_f32_16x16x32_bf16(wf, xf, acc1[tt], 0, 0, 0);
      }
    }
  };
  // ph2 step: A = W2 rows (out), B = H token tiles. st = k-half (0/1)
  auto ph2 = [&](int st) {
#pragma unroll
    for (int kk = 0; kk < 2; ++kk) {
      int wc = kk * 32 + ksel;
      short8 wf[2];
#pragma unroll
      for (int ot = 0; ot < 2; ++ot) {
        int wrow = wn * 32 + ot * 16 + rsel;
        wf[ot] = *(const short8*)&Ws[wrow * 64 + SWZ(wrow, wc)];
      }
      int kc = st * 64 + kk * 32 + ksel;
#pragma unroll
      for (int tt = 0; tt < 4; ++tt) {
        int tok = tt * 16 + rsel;
        short4v lo = *(const short4v*)&Hs[tok][SWZ4(tok, kc)];
        short4v hi = *(const short4v*)&Hs[tok][SWZ4(tok, kc + 4)];
        short8 hf = {lo[0], lo[1], lo[2], lo[3], hi[0], hi[1], hi[2], hi[3]};
#pragma unroll
        for (int ot = 0; ot < 2; ++ot)
          acc2[ot][tt] = __builtin_amdgcn_mfma_f32_16x16x32_bf16(wf[ot], hf, acc2[ot][tt], 0, 0, 0);
      }
    }
  };

  for (int hc = 0; hc < 8; ++hc) {
    const u16* W1c = W1 + (size_t)hc * 128 * 256;
    const u16* W2c = W2 + hc * 128;
    // W2 st0 loads (latency hidden under all of phase 1)
    short8 q0 = *(const short8*)(W2c + (size_t)w2r * 1024 + w2c);
    short8 q1 = *(const short8*)(W2c + (size_t)w2r * 1024 + w2c + 8);
    short8 q2 = *(const short8*)(W2c + (size_t)w2r * 1024 + w2c + 16);
    short8 q3 = *(const short8*)(W2c + (size_t)w2r * 1024 + w2c + 24);

#pragma unroll
    for (int i = 0; i < 4; ++i) acc1[i] = zero;

    // ---- phase 1: 4 stages of BK=64, dbuf ----
    *(short8*)&Ws[w1r * 64 + SWZ(w1r, w1c)] = w1a;
    *(short8*)&Ws[w1r * 64 + SWZ(w1r, w1c + 8)] = w1b;
    short8 p0 = *(const short8*)(W1c + (size_t)w1r * 256 + 64 + w1c);
    short8 p1 = *(const short8*)(W1c + (size_t)w1r * 256 + 64 + w1c + 8);
    __syncthreads();                                           // B1
    short8 s0 = *(const short8*)(W1c + (size_t)w1r * 256 + 128 + w1c);
    short8 s1 = *(const short8*)(W1c + (size_t)w1r * 256 + 128 + w1c + 8);
    ph1(0, 0);
    *(short8*)&Ws[8192 + w1r * 64 + SWZ(w1r, w1c)] = p0;
    *(short8*)&Ws[8192 + w1r * 64 + SWZ(w1r, w1c + 8)] = p1;
    __syncthreads();                                           // B2
    p0 = *(const short8*)(W1c + (size_t)w1r * 256 + 192 + w1c);
    p1 = *(const short8*)(W1c + (size_t)w1r * 256 + 192 + w1c + 8);
    ph1(1, 1);
    *(short8*)&Ws[w1r * 64 + SWZ(w1r, w1c)] = s0;
    *(short8*)&Ws[w1r * 64 + SWZ(w1r, w1c + 8)] = s1;
    __syncthreads();                                           // B3
    ph1(2, 0);
    *(short8*)&Ws[8192 + w1r * 64 + SWZ(w1r, w1c)] = p0;
    *(short8*)&Ws[8192 + w1r * 64 + SWZ(w1r, w1c + 8)] = p1;
    __syncthreads();                                           // B4
    ph1(3, 1);

    // ---- gelu -> Hs (packed ushort4, SWZ4; lane holds 4 hid x 1 tok) ----
#pragma unroll
    for (int tt = 0; tt < 4; ++tt) {
      int tok = tt * 16 + rsel;
      int hid0 = wn * 16 + (lane >> 4) * 4;
      u16 hv[4];
#pragma unroll
      for (int r = 0; r < 4; ++r) {
        float v = acc1[tt][r] + B1[hc * 128 + hid0 + r];
        float u = 1.5957691216057308f * (v + 0.044715f * v * v * v);
        hv[r] = bfbits(v / (1.f + __expf(-u)));
      }
      *(ushort4*)&Hs[tok][SWZ4(tok, hid0)] = make_ushort4(hv[0], hv[1], hv[2], hv[3]);
    }
    __syncthreads();                                           // B5 (Ws free + Hs ready)

    // ---- phase 2: 2 halves of BK=64, Ws reused flat [256][64] ----
    *(short8*)&Ws[w2r * 64 + SWZ(w2r, w2c)] = q0;
    *(short8*)&Ws[w2r * 64 + SWZ(w2r, w2c + 8)] = q1;
    *(short8*)&Ws[w2r * 64 + SWZ(w2r, w2c + 16)] = q2;
    *(short8*)&Ws[w2r * 64 + SWZ(w2r, w2c + 24)] = q3;
    q0 = *(const short8*)(W2c + (size_t)w2r * 1024 + 64 + w2c);
    q1 = *(const short8*)(W2c + (size_t)w2r * 1024 + 64 + w2c + 8);
    q2 = *(const short8*)(W2c + (size_t)w2r * 1024 + 64 + w2c + 16);
    q3 = *(const short8*)(W2c + (size_t)w2r * 1024 + 64 + w2c + 24);
    __syncthreads();                                           // B6
    ph2(0);
    __syncthreads();                                           // B7
    *(short8*)&Ws[w2r * 64 + SWZ(w2r, w2c)] = q0;
    *(short8*)&Ws[w2r * 64 + SWZ(w2r, w2c + 8)] = q1;
    *(short8*)&Ws[w2r * 64 + SWZ(w2r, w2c + 16)] = q2;
    *(short8*)&Ws[w2r * 64 + SWZ(w2r, w2c + 24)] = q3;
    if (hc < 7) {   // next-hc W1 st0 loads hide under phase-2 st1
      w1a = *(const short8*)(W1 + (size_t)((hc + 1) * 128 + w1r) * 256 + w1c);
      w1b = *(const short8*)(W1 + (size_t)((hc + 1) * 128 + w1r) * 256 + w1c + 8);
    }
    __syncthreads();                                           // B8
    ph2(1);
    __syncthreads();                                           // B9 (Ws+Hs free)
  }

  // ---- epilogue: yslot = gate * (Y + b2), float4 full-line stores ----
#pragma unroll
  for (int tt = 0; tt < 4; ++tt) {
    int grow = row0 + tt * 16 + rsel;
    if (grow < Meff) {
      int tk = gidx[grow];
      float gt = gates[(size_t)tk * 6 + e];
#pragma unroll
      for (int ot = 0; ot < 2; ++ot) {
        int out0 = wn * 32 + ot * 16 + (lane >> 4) * 4;
        float4 w4 = make_float4(gt * (acc2[ot][tt][0] + B2[out0]),
                                gt * (acc2[ot][tt][1] + B2[out0 + 1]),
                                gt * (acc2[ot][tt][2] + B2[out0 + 2]),
                                gt * (acc2[ot][tt][3] + B2[out0 + 3]));
        *(float4*)&yslot[(size_t)(hbase + grow) * 256 + out0] = w4;
      }
    }
  }
}

// ---------------------------------------------------------------------------
// LayerNorm over E=256: wave per token; bf16 out
// ---------------------------------------------------------------------------
__global__ __launch_bounds__(256) void ln_kernel(const float* __restrict__ in,
    const float* __restrict__ g, const float* __restrict__ b, u16* __restrict__ oh)
{
  const int lane = threadIdx.x & 63;
  const int t = blockIdx.x * 4 + (threadIdx.x >> 6);
  const float4 v = *(const float4*)(in + (size_t)t * 256 + lane * 4);
  float s = v.x + v.y + v.z + v.w;
  float sq = v.x * v.x + v.y * v.y + v.z * v.z + v.w * v.w;
#pragma unroll
  for (int o = 32; o >= 1; o >>= 1) {
    s  += __shfl_xor(s,  o, 64);
    sq += __shfl_xor(sq, o, 64);
  }
  float mu = s * (1.f / 256.f);
  float var = sq * (1.f / 256.f) - mu * mu;
  float rstd = rsqrtf(var + 1e-5f);
  const float4 gv = *(const float4*)(g + lane * 4);
  const float4 bv = *(const float4*)(b + lane * 4);
  *(ushort4*)(oh + (size_t)t * 256 + lane * 4) = make_ushort4(
      bfbits((v.x - mu) * rstd * gv.x + bv.x), bfbits((v.y - mu) * rstd * gv.y + bv.y),
      bfbits((v.z - mu) * rstd * gv.z + bv.z), bfbits((v.w - mu) * rstd * gv.w + bv.w));
}

// ---------------------------------------------------------------------------
// Fused slot-combine + LayerNorm: moe[t] = yslot[s0]+yslot[s1]; x2 = LN(moe)
// ---------------------------------------------------------------------------
__global__ __launch_bounds__(256) void ln2_combine(const float* __restrict__ yslot,
    const int* __restrict__ invslot,
    const float* __restrict__ g, const float* __restrict__ b, float* __restrict__ outf)
{
  const int lane = threadIdx.x & 63;
  const int t = blockIdx.x * 4 + (threadIdx.x >> 6);
  const int s0 = invslot[t * 2], s1 = invslot[t * 2 + 1];
  const float4 a = *(const float4*)(yslot + (size_t)s0 * 256 + lane * 4);
  const float4 c = *(const float4*)(yslot + (size_t)s1 * 256 + lane * 4);
  float4 v = make_float4(a.x + c.x, a.y + c.y, a.z + c.z, a.w + c.w);
  float s = v.x + v.y + v.z + v.w;
  float sq = v.x * v.x + v.y * v.y + v.z * v.z + v.w * v.w;
#pragma unroll
  for (int o = 32; o >= 1; o >>= 1) {
    s  += __shfl_xor(s,  o, 64);
    sq += __shfl_xor(sq, o, 64);
  }
  float mu = s * (1.f / 256.f);
  float var = sq * (1.f / 256.f) - mu * mu;
  float rstd = rsqrtf(var + 1e-5f);
  const float4 gv = *(const float4*)(g + lane * 4);
  const float4 bv = *(const float4*)(b + lane * 4);
  *(float4*)(outf + (size_t)t * 256 + lane * 4) = make_float4(
      (v.x - mu) * rstd * gv.x + bv.x, (v.y - mu) * rstd * gv.y + bv.y,
      (v.z - mu) * rstd * gv.z + bv.z, (v.w - mu) * rstd * gv.w + bv.w);
}

// ---------------------------------------------------------------------------
// MFMA attention: one block per (b,h), 4 waves, 13 m-tiles of 16 q-rows.
// ao written split (hi+lo): feeds wo -> x1f -> router (gate precision).
// ---------------------------------------------------------------------------
__global__ __launch_bounds__(256) void attn_mfma(const u16* __restrict__ qkvb,
                                                 u16* __restrict__ aoh, u16* __restrict__ aol) {
  __shared__ u16 Qs[208][40];
  __shared__ u16 Ks[208][40];
  __shared__ u16 Vt[32][256];
  __shared__ u16 Ps[4][16][232];
  const int tid = threadIdx.x, lane = tid & 63, wave = tid >> 6;
  const int b = blockIdx.x >> 3, h = blockIdx.x & 7;
  const size_t base = (size_t)b * 196 * 768 + h * 32;
  const short8 z8 = {0, 0, 0, 0, 0, 0, 0, 0};

  for (int idx = tid; idx < 832; idx += 256) {
    int r = idx >> 2, c = (idx & 3) * 8;
    short8 q = z8, k = z8;
    if (r < 196) {
      q = *(const short8*)(qkvb + base + (size_t)r * 768 + c);
      k = *(const short8*)(qkvb + base + (size_t)r * 768 + 256 + c);
    }
    *(short8*)&Qs[r][c] = q;
    *(short8*)&Ks[r][c] = k;
  }
  for (int idx = tid; idx < 32 * 224; idx += 256) {
    int c = idx & 31, k = idx >> 5;
    u16 v = 0;
    if (k < 196) v = qkvb[base + (size_t)k * 768 + 512 + c];
    Vt[c][k ^ ((c & 7) << 3)] = v;
  }
  {
    int r = lane >> 2, c0 = 208 + (lane & 3) * 4;
    Ps[wave][r][c0] = 0; Ps[wave][r][c0 + 1] = 0; Ps[wave][r][c0 + 2] = 0; Ps[wave][r][c0 + 3] = 0;
  }
  __syncthreads();

  const int rsel = lane & 15, ksel = (lane >> 4) * 8;
  const f32x4 zero = {0.f, 0.f, 0.f, 0.f};

  for (int mt = wave; mt < 13; mt += 4) {
    short8 aq = *(const short8*)&Qs[mt * 16 + rsel][ksel];
    f32x4 sacc[13];
#pragma unroll
    for (int n = 0; n < 13; ++n)
      sacc[n] = __builtin_amdgcn_mfma_f32_16x16x32_bf16(
          aq, *(const short8*)&Ks[n * 16 + rsel][ksel], zero, 0, 0, 0);

#pragma unroll
    for (int r = 0; r < 4; ++r) {
      float mv = -1e30f;
#pragma unroll
      for (int n = 0; n < 13; ++n) {
        float sv = sacc[n][r] * 0.17677669529663687f;
        sacc[n][r] = sv;
        if (n * 16 + rsel < 196) mv = fmaxf(mv, sv);
      }
      mv = fmaxf(mv, __shfl_xor(mv, 1, 64));
      mv = fmaxf(mv, __shfl_xor(mv, 2, 64));
      mv = fmaxf(mv, __shfl_xor(mv, 4, 64));
      mv = fmaxf(mv, __shfl_xor(mv, 8, 64));
      float sm = 0.f;
#pragma unroll
      for (int n = 0; n < 13; ++n) {
        float p = (n * 16 + rsel < 196) ? __expf(sacc[n][r] - mv) : 0.f;
        sacc[n][r] = p;
        sm += p;
      }
      sm += __shfl_xor(sm, 1, 64);
      sm += __shfl_xor(sm, 2, 64);
      sm += __shfl_xor(sm, 4, 64);
      sm += __shfl_xor(sm, 8, 64);
      float inv = 1.f / sm;
      int prow = (lane >> 4) * 4 + r;
#pragma unroll
      for (int n = 0; n < 13; ++n)
        Ps[wave][prow][n * 16 + rsel] = bfbits(sacc[n][r] * inv);
    }

    f32x4 oacc[2] = {zero, zero};
#pragma unroll
    for (int kk = 0; kk < 7; ++kk) {
      short8 ap = *(const short8*)&Ps[wave][rsel][kk * 32 + ksel];
#pragma unroll
      for (int nt = 0; nt < 2; ++nt) {
        int d = nt * 16 + rsel;
        short8 bv = *(const short8*)&Vt[d][(kk * 32 + ksel) ^ ((d & 7) << 3)];
        oacc[nt] = __builtin_amdgcn_mfma_f32_16x16x32_bf16(ap, bv, oacc[nt], 0, 0, 0);
      }
    }
#pragma unroll
    for (int nt = 0; nt < 2; ++nt) {
#pragma unroll
      for (int r = 0; r < 4; ++r) {
        int row = mt * 16 + (lane >> 4) * 4 + r;
        if (row < 196) {
          size_t oi = ((size_t)b * 196 + row) * 256 + h * 32 + nt * 16 + rsel;
          u16 hh, ll; fsplit(oacc[nt][r], hh, ll);
          aoh[oi] = hh; aol[oi] = ll;
        }
      }
    }
  }
}

// ---------------------------------------------------------------------------
// Router: wave per token; 6 logits, softmax, top-2 -> dense gates [T,6]
// ---------------------------------------------------------------------------
__global__ __launch_bounds__(256) void router_kernel(const float* __restrict__ x1,
    const float* __restrict__ rw, const float* __restrict__ rb, float* __restrict__ gates)
{
  const int lane = threadIdx.x & 63;
  const int t = blockIdx.x * 4 + (threadIdx.x >> 6);
  const float4 xv = *(const float4*)(x1 + (size_t)t * 256 + lane * 4);
  float logit[6];
#pragma unroll
  for (int e = 0; e < 6; ++e) {
    const float4 wv = *(const float4*)(rw + e * 256 + lane * 4);
    float p = xv.x * wv.x + xv.y * wv.y + xv.z * wv.z + xv.w * wv.w;
#pragma unroll
    for (int o = 32; o >= 1; o >>= 1) p += __shfl_xor(p, o, 64);
    logit[e] = p + rb[e];
  }
  float mx = logit[0];
#pragma unroll
  for (int e = 1; e < 6; ++e) mx = fmaxf(mx, logit[e]);
  float pe[6], sum = 0.f;
#pragma unroll
  for (int e = 0; e < 6; ++e) { pe[e] = __expf(logit[e] - mx); sum += pe[e]; }
  float inv = 1.f / sum;
  int i1 = 0; float p1 = pe[0];
#pragma unroll
  for (int e = 1; e < 6; ++e) if (pe[e] > p1) { p1 = pe[e]; i1 = e; }
  int i2 = -1; float p2 = -1.f;
#pragma unroll
  for (int e = 0; e < 6; ++e) if (e != i1 && pe[e] > p2) { p2 = pe[e]; i2 = e; }
  if (lane < 6)
    gates[(size_t)t * 6 + lane] = (lane == i1) ? p1 * inv : ((lane == i2) ? p2 * inv : 0.f);
}

// ---------------------------------------------------------------------------
// Scatter: build per-expert token lists (block-aggregated atomics)
// ---------------------------------------------------------------------------
__global__ __launch_bounds__(256) void scatter_kernel(const float* __restrict__ gates,
                                                      int* __restrict__ cnt, int* __restrict__ idx) {
  __shared__ int lcnt[6], lbase[6];
  const int t = blockIdx.x * 256 + threadIdx.x;
  if (threadIdx.x < 6) lcnt[threadIdx.x] = 0;
  __syncthreads();
  float g[6]; int lpos[6];
#pragma unroll
  for (int e = 0; e < 6; ++e) {
    g[e] = gates[(size_t)t * 6 + e];
    if (g[e] > 0.f) lpos[e] = atomicAdd(&lcnt[e], 1);
  }
  __syncthreads();
  if (threadIdx.x < 6) lbase[threadIdx.x] = atomicAdd(&cnt[threadIdx.x], lcnt[threadIdx.x]);
  __syncthreads();
#pragma unroll
  for (int e = 0; e < 6; ++e)
    if (g[e] > 0.f) idx[(size_t)e * T_TOK + lbase[e] + lpos[e]] = t;
}

// exclusive prefix over the 6 expert counts -> segment bases in slot buffer
__global__ void prefix6_kernel(const int* __restrict__ cnt, int* __restrict__ base) {
  if (threadIdx.x == 0) {
    int s = 0;
#pragma unroll
    for (int e = 0; e < 6; ++e) { base[e] = s; s += cnt[e]; }
  }
}

// token -> its 2 slot positions in the concatenated expert segments
__global__ __launch_bounds__(256) void slotmap_kernel(const int* __restrict__ idx,
    const int* __restrict__ cnt, const int* __restrict__ base,
    int* __restrict__ nslot, int* __restrict__ invslot) {
  const int e = blockIdx.y;
  const int p = blockIdx.x * 256 + threadIdx.x;
  if (p < cnt[e]) {
    int t = idx[(size_t)e * T_TOK + p];
    int j = atomicAdd(&nslot[t], 1);
    invslot[(size_t)t * 2 + j] = base[e] + p;
  }
}

// ---------------------------------------------------------------------------
// Mean-pool over tokens, then classifier head (fp32)
// ---------------------------------------------------------------------------
__global__ __launch_bounds__(256) void pool_kernel(const float* __restrict__ x2, float* __restrict__ pooled) {
  int b = blockIdx.x, e = threadIdx.x;
  float s = 0.f;
  for (int n = 0; n < 196; ++n) s += x2[((size_t)b * 196 + n) * 256 + e];
  pooled[(size_t)b * 256 + e] = s * (1.f / 196.f);
}

__global__ __launch_bounds__(256) void head_kernel(const float* __restrict__ pooled,
    const float* __restrict__ hw, const float* __restrict__ hb, float* __restrict__ out) {
  __shared__ float p[256];
  int b = blockIdx.x;
  p[threadIdx.x] = pooled[(size_t)b * 256 + threadIdx.x];
  __syncthreads();
  for (int cls = threadIdx.x; cls < 1000; cls += 256) {
    const float* w = hw + (size_t)cls * 256;
    float s = hb[cls];
    for (int k = 0; k < 256; k += 4)
      s += p[k] * w[k] + p[k + 1] * w[k + 1] + p[k + 2] * w[k + 2] + p[k + 3] * w[k + 3];
    out[(size_t)b * 1000 + cls] = s;
  }
}

// ---------------------------------------------------------------------------
// Weight prep: f32 -> hi/lo bf16 split; transpose+cast (hi-only) for MoE
// ---------------------------------------------------------------------------
__global__ void cast_split_kernel(const float* __restrict__ in,
                                  u16* __restrict__ oh, u16* __restrict__ ol, int n4) {
  int id = blockIdx.x * 256 + threadIdx.x;
  if (id >= n4) return;
  float4 v = ((const float4*)in)[id];
  u16 h0, l0, h1, l1, h2, l2, h3, l3;
  fsplit(v.x, h0, l0); fsplit(v.y, h1, l1); fsplit(v.z, h2, l2); fsplit(v.w, h3, l3);
  ((ushort4*)oh)[id] = make_ushort4(h0, h1, h2, h3);
  ((ushort4*)ol)[id] = make_ushort4(l0, l1, l2, l3);
}

__global__ __launch_bounds__(256) void transpose_cast(const float* __restrict__ in,
    u16* __restrict__ oh, int R, int C) {
  __shared__ float tile[32][33];
  const int e = blockIdx.z;
  const int bc = blockIdx.x * 32, br = blockIdx.y * 32;
  const int tx = threadIdx.x & 31, ty = threadIdx.x >> 5;
  const float* src = in + (size_t)e * R * C;
#pragma unroll
  for (int i = 0; i < 32; i += 8)
    tile[ty + i][tx] = src[(size_t)(br + ty + i) * C + bc + tx];
  __syncthreads();
#pragma unroll
  for (int i = 0; i < 32; i += 8) {
    size_t di = (size_t)e * R * C + (size_t)(bc + ty + i) * R + br + tx;
    oh[di] = bfbits(tile[tx][ty + i]);
  }
}

// ---------------------------------------------------------------------------
extern "C" void kernel_launch(void* const* d_in, const int* in_sizes, int n_in,
                              void* d_out, int out_size, void* d_ws, size_t ws_size,
                              hipStream_t stream) {
  (void)in_sizes; (void)n_in; (void)out_size; (void)ws_size;
  const float* x      = (const float*)d_in[0];
  const float* conv_w = (const float*)d_in[1];
  const float* conv_b = (const float*)d_in[2];
  const float* pos    = (const float*)d_in[3];
  const float* ln1_g  = (const float*)d_in[4];
  const float* ln1_b  = (const float*)d_in[5];
  const float* wqkv   = (const float*)d_in[6];
  const float* bqkv   = (const float*)d_in[7];
  const float* wo     = (const float*)d_in[8];
  const float* bo     = (const float*)d_in[9];
  const float* rw     = (const float*)d_in[10];
  const float* rb     = (const float*)d_in[11];
  const float* w1     = (const float*)d_in[12];
  const float* b1     = (const float*)d_in[13];
  const float* w2     = (const float*)d_in[14];
  const float* b2     = (const float*)d_in[15];
  const float* ln2_g  = (const float*)d_in[16];
  const float* ln2_b  = (const float*)d_in[17];
  const float* hw     = (const float*)d_in[18];
  const float* hb     = (const float*)d_in[19];
  float* out = (float*)d_out;

  const int T = T_TOK;
  char* ws = (char*)d_ws;
  size_t off = 0;
  auto alloc = [&](size_t bytes) -> void* {
    void* p = ws + off;
    off += (bytes + 255) & ~(size_t)255;
    return p;
  };
  // region 0: tok+xnh+qkvb -> reused as x2 after qkv consumed
  float* tok    = (float*)alloc((size_t)T * 256 * 4);
  u16*   xnh    = (u16*)  alloc((size_t)T * 256 * 2);
  u16*   qkvb   = (u16*)  alloc((size_t)T * 768 * 2);
  // region 1: aoh+aol+x1f == exactly [2T,256] f32 -> reused as yslot
  u16*   aoh    = (u16*)  alloc((size_t)T * 256 * 2);
  u16*   aol    = (u16*)  alloc((size_t)T * 256 * 2);
  float* x1f    = (float*)alloc((size_t)T * 256 * 4);
  u16*   x1h    = (u16*)  alloc((size_t)T * 256 * 2);
  float* gates  = (float*)alloc((size_t)T * 6 * 4);
  int*   idx    = (int*)  alloc((size_t)6 * T * 4);
  int*   cnt    = (int*)  alloc(256);
  int*   base   = (int*)  alloc(256);
  int*   nslot  = (int*)  alloc((size_t)T * 4);
  int*   invslot= (int*)  alloc((size_t)2 * T * 4);
  float* pooled = (float*)alloc((size_t)128 * 256 * 4);
  u16*   cwh    = (u16*)  alloc((size_t)196608 * 2);
  u16*   cwl    = (u16*)  alloc((size_t)196608 * 2);
  u16*   wqh    = (u16*)  alloc((size_t)196608 * 2);
  u16*   wql    = (u16*)  alloc((size_t)196608 * 2);
  u16*   woh    = (u16*)  alloc((size_t)65536 * 2);
  u16*   wol    = (u16*)  alloc((size_t)65536 * 2);
  u16*   w1th   = (u16*)  alloc((size_t)6 * 262144 * 2);
  u16*   w2th   = (u16*)  alloc((size_t)6 * 262144 * 2);
  // aliases (lifetimes disjoint):
  float* yslot = (float*)aoh;   // [2T,256] f32 (region 1; exact fit)
  float* x2    = (float*)ws;    // [T,256] f32 (region 0 head; tok dead by then)

  // --- weight prep (router-path weights hi+lo; MoE weights hi-only) ---
  cast_split_kernel<<<192, 256, 0, stream>>>(conv_w, cwh, cwl, 49152);
  cast_split_kernel<<<192, 256, 0, stream>>>(wqkv, wqh, wql, 49152);
  cast_split_kernel<<<64, 256, 0, stream>>>(wo, woh, wol, 16384);
  transpose_cast<<<dim3(32, 8, 6), 256, 0, stream>>>(w1, w1th, 256, 1024);  // [e][n][k]
  transpose_cast<<<dim3(8, 32, 6), 256, 0, stream>>>(w2, w2th, 1024, 256);  // [e][n][k]

  // --- patch embedding (fused im2col + split-A GEMM) ---
  gemm_patch<<<dim3(196, 2), 256, 0, stream>>>(x, cwh, cwl, conv_b, pos, tok);

  // --- attention block ---
  ln_kernel<<<6272, 256, 0, stream>>>(tok, ln1_g, ln1_b, xnh);
  gemm_bs<5, false><<<dim3(196, 6), 256, 0, stream>>>(xnh, nullptr, wqh, wql, T, 768, 256,
      bqkv, nullptr, nullptr, qkvb);
  attn_mfma<<<1024, 256, 0, stream>>>(qkvb, aoh, aol);
  gemm_bs<2, true><<<dim3(196, 2), 256, 0, stream>>>(aoh, aol, woh, wol, T, 256, 256,
      bo, tok, x1f, x1h);

  // --- MoE (top-2 sparse, fused GEMM1+gelu+GEMM2, 2 blocks/CU) ---
  router_kernel<<<6272, 256, 0, stream>>>(x1f, rw, rb, gates);
  hipMemsetAsync(cnt, 0, 256, stream);
  scatter_kernel<<<98, 256, 0, stream>>>(gates, cnt, idx);
  prefix6_kernel<<<1, 64, 0, stream>>>(cnt, base);
  hipMemsetAsync(nslot, 0, (size_t)T * 4, stream);
  slotmap_kernel<<<dim3(98, 6), 256, 0, stream>>>(idx, cnt, base, nslot, invslot);
  moe_fused<<<dim3(392, 1, 6), 512, 0, stream>>>(x1h, w1th, w2th,
      b1, b2, gates, idx, cnt, base, yslot);

  // --- final norm (fused slot combine), pool, head ---
  ln2_combine<<<6272, 256, 0, stream>>>(yslot, invslot, ln2_g, ln2_b, x2);
  pool_kernel<<<128, 256, 0, stream>>>(x2, pooled);
  head_kernel<<<128, 256, 0, stream>>>(pooled, hw, hb, out);
}

// Round 16
// 381.979 us; speedup vs baseline: 1.0601x; 1.0271x over previous
//
#include <hip/hip_runtime.h>
#include <hip/hip_bf16.h>

typedef unsigned short u16;
typedef short short8 __attribute__((ext_vector_type(8)));
typedef short short4v __attribute__((ext_vector_type(4)));
typedef float f32x4 __attribute__((ext_vector_type(4)));

#define T_TOK 25088   // 128*196
#define NTOK 196
// 16B-chunk XOR swizzle (T2-style)
#define SWZ(r, c) ((((((c) >> 3) ^ ((r) & 7)) << 3)) | ((c) & 7))
// 8B-chunk XOR swizzle (for Hs: packed ushort4 writes + paired b64 reads)
#define SWZ4(r, c) ((((((c) >> 2) & 16) | ((((c) >> 2) ^ (r)) & 15)) << 2) | ((c) & 3))

__device__ __forceinline__ u16 bfbits(float v) {
  __hip_bfloat16 h = __float2bfloat16(v);
  return *reinterpret_cast<u16*>(&h);
}
__device__ __forceinline__ float b2f(u16 u) {
  __hip_bfloat16 h = *reinterpret_cast<__hip_bfloat16*>(&u);
  return __bfloat162float(h);
}
// near-fp32 as hi+lo bf16 pair (Ootomo split)
__device__ __forceinline__ void fsplit(float v, u16& hi, u16& lo) {
  hi = bfbits(v);
  lo = bfbits(v - b2f(hi));
}

// ---------------------------------------------------------------------------
// Dense GEMM (r9/r11): C[M,N] = A[M,K] @ (Bh+Bl)[N,K]^T + bias.
// A split (3 MFMA/frag) when SPLITA — router-input path (wo).
// 128x128 tile, BK=32, 256 threads (4 waves 2x2), reg-staged 1-deep prefetch.
// EPI: 2 +resid->f32+bf16 | 5 ->bf16
// ---------------------------------------------------------------------------
template<int EPI, bool SPLITA>
__global__ __launch_bounds__(256) void gemm_bs(
    const u16* __restrict__ A, const u16* __restrict__ Al,
    const u16* __restrict__ Bh, const u16* __restrict__ Bl,
    int M, int N, int K,
    const float* __restrict__ bias, const float* __restrict__ extra,
    float* __restrict__ outf, u16* __restrict__ obh)
{
  __shared__ u16 As[128][40];                      // +8 pad: 2-way banks
  __shared__ u16 Asl[SPLITA ? 128 : 1][40];
  __shared__ u16 Bsh[128][40], Bsl[128][40];
  const int tid = threadIdx.x;
  const int lane = tid & 63, wave = tid >> 6;
  const int wm = wave >> 1, wn = wave & 1;
  const int row0 = blockIdx.x * 128, col0 = blockIdx.y * 128;

  const int r0 = tid >> 2, r1 = r0 + 64, co = (tid & 3) * 8;
  const int ar0 = row0 + r0, ar1 = row0 + r1;

  f32x4 acc[4][4];
  const f32x4 zero = {0.f, 0.f, 0.f, 0.f};
#pragma unroll
  for (int i = 0; i < 4; ++i)
#pragma unroll
    for (int j = 0; j < 4; ++j) acc[i][j] = zero;

  const int rsel = lane & 15, ksel = (lane >> 4) * 8;

  short8 ra, rl, rb0, rb1, rc0, rc1;
  auto issue = [&](int k0) {
    ra = *(const short8*)(A + (size_t)ar0 * K + k0 + co);
    rl = *(const short8*)(A + (size_t)ar1 * K + k0 + co);
    rb0 = *(const short8*)(Bh + (size_t)(col0 + r0) * K + k0 + co);
    rb1 = *(const short8*)(Bh + (size_t)(col0 + r1) * K + k0 + co);
    rc0 = *(const short8*)(Bl + (size_t)(col0 + r0) * K + k0 + co);
    rc1 = *(const short8*)(Bl + (size_t)(col0 + r1) * K + k0 + co);
  };
  short8 sa, sl;
  auto issueS = [&](int k0) {
    if constexpr (SPLITA) {
      sa = *(const short8*)(Al + (size_t)ar0 * K + k0 + co);
      sl = *(const short8*)(Al + (size_t)ar1 * K + k0 + co);
    }
  };
  auto commit = [&]() {
    *(short8*)&As[r0][co] = ra;
    *(short8*)&As[r1][co] = rl;
    if constexpr (SPLITA) {
      *(short8*)&Asl[r0][co] = sa;
      *(short8*)&Asl[r1][co] = sl;
    }
    *(short8*)&Bsh[r0][co] = rb0;
    *(short8*)&Bsh[r1][co] = rb1;
    *(short8*)&Bsl[r0][co] = rc0;
    *(short8*)&Bsl[r1][co] = rc1;
  };

  issue(0);
  issueS(0);
  commit();
  __syncthreads();

  for (int k0 = 0;;) {
    const bool more = (k0 + 32 < K);
    if (more) { issue(k0 + 32); issueS(k0 + 32); }
    short8 af[4], al4[4], bh4[4], bl4[4];
#pragma unroll
    for (int i = 0; i < 4; ++i) {
      af[i] = *(const short8*)&As[wm * 64 + i * 16 + rsel][ksel];
      if constexpr (SPLITA) al4[i] = *(const short8*)&Asl[wm * 64 + i * 16 + rsel][ksel];
    }
#pragma unroll
    for (int j = 0; j < 4; ++j) {
      bh4[j] = *(const short8*)&Bsh[wn * 64 + j * 16 + rsel][ksel];
      bl4[j] = *(const short8*)&Bsl[wn * 64 + j * 16 + rsel][ksel];
    }
#pragma unroll
    for (int i = 0; i < 4; ++i)
#pragma unroll
      for (int j = 0; j < 4; ++j) {
        acc[i][j] = __builtin_amdgcn_mfma_f32_16x16x32_bf16(af[i], bh4[j], acc[i][j], 0, 0, 0);
        if constexpr (SPLITA)
          acc[i][j] = __builtin_amdgcn_mfma_f32_16x16x32_bf16(al4[i], bh4[j], acc[i][j], 0, 0, 0);
        acc[i][j] = __builtin_amdgcn_mfma_f32_16x16x32_bf16(af[i], bl4[j], acc[i][j], 0, 0, 0);
      }
    k0 += 32;
    if (!more) break;
    __syncthreads();
    commit();
    __syncthreads();
  }

#pragma unroll
  for (int i = 0; i < 4; ++i) {
#pragma unroll
    for (int j = 0; j < 4; ++j) {
#pragma unroll
      for (int r = 0; r < 4; ++r) {
        int grow = row0 + wm * 64 + i * 16 + (lane >> 4) * 4 + r;   // token
        int gcol = col0 + wn * 64 + j * 16 + rsel;                  // feature
        float v = acc[i][j][r] + bias[gcol];
        size_t oi = (size_t)grow * N + gcol;
        if constexpr (EPI == 2) {
          v += extra[oi];                                  // residual
          outf[oi] = v;
          obh[oi] = bfbits(v);
        } else if constexpr (EPI == 5) {
          obh[oi] = bfbits(v);
        }
      }
    }
  }
}

// ---------------------------------------------------------------------------
// Patch-embed GEMM with FUSED im2col: C[T,256] = A[T,768] @ convW^T + b + pos,
// where A rows are computed from x[B,3,224,224] on the fly (hi/lo split in
// LDS). k = c*256 + p*16 + q; a BK=32 step = one channel c, rows p, p+1.
// ---------------------------------------------------------------------------
__global__ __launch_bounds__(256) void gemm_patch(
    const float* __restrict__ xin,
    const u16* __restrict__ Bh, const u16* __restrict__ Bl,
    const float* __restrict__ bias, const float* __restrict__ pos,
    float* __restrict__ outf)
{
  __shared__ u16 As[128][40], Asl[128][40];
  __shared__ u16 Bsh[128][40], Bsl[128][40];
  const int tid = threadIdx.x;
  const int lane = tid & 63, wave = tid >> 6;
  const int wm = wave >> 1, wn = wave & 1;
  const int row0 = blockIdx.x * 128, col0 = blockIdx.y * 128;
  const int rsel = lane & 15, ksel = (lane >> 4) * 8;
  const int K = 768, N = 256;

  const int ar = tid >> 1, ph = tid & 1;
  const float* srcbase;
  {
    int t = row0 + ar;
    int b = t / 196, n = t - b * 196;
    int gh = n / 14, gw = n - gh * 14;
    srcbase = xin + ((size_t)(b * 3) * 224 + gh * 16) * 224 + gw * 16;
  }
  const int br0 = tid >> 2, br1 = br0 + 64, bco = (tid & 3) * 8;

  f32x4 acc[4][4];
  const f32x4 zero = {0.f, 0.f, 0.f, 0.f};
#pragma unroll
  for (int i = 0; i < 4; ++i)
#pragma unroll
    for (int j = 0; j < 4; ++j) acc[i][j] = zero;

  float4 fa0, fa1, fa2, fa3;           // A prefetch (16 floats)
  short8 rb0, rb1, rc0, rc1;           // B prefetch
  auto issue = [&](int k0) {
    int c = k0 >> 8, p = ((k0 >> 4) & 15) + ph;
    const float* s = srcbase + ((size_t)c * 224 + p) * 224;
    fa0 = *(const float4*)(s);
    fa1 = *(const float4*)(s + 4);
    fa2 = *(const float4*)(s + 8);
    fa3 = *(const float4*)(s + 12);
    rb0 = *(const short8*)(Bh + (size_t)(col0 + br0) * K + k0 + bco);
    rb1 = *(const short8*)(Bh + (size_t)(col0 + br1) * K + k0 + bco);
    rc0 = *(const short8*)(Bl + (size_t)(col0 + br0) * K + k0 + bco);
    rc1 = *(const short8*)(Bl + (size_t)(col0 + br1) * K + k0 + bco);
  };
  auto commit = [&]() {
    float f[16] = {fa0.x, fa0.y, fa0.z, fa0.w, fa1.x, fa1.y, fa1.z, fa1.w,
                   fa2.x, fa2.y, fa2.z, fa2.w, fa3.x, fa3.y, fa3.z, fa3.w};
    u16 hv[16], lv[16];
#pragma unroll
    for (int j = 0; j < 16; ++j) fsplit(f[j], hv[j], lv[j]);
    short8 h0 = {(short)hv[0], (short)hv[1], (short)hv[2], (short)hv[3],
                 (short)hv[4], (short)hv[5], (short)hv[6], (short)hv[7]};
    short8 h1 = {(short)hv[8], (short)hv[9], (short)hv[10], (short)hv[11],
                 (short)hv[12], (short)hv[13], (short)hv[14], (short)hv[15]};
    short8 l0 = {(short)lv[0], (short)lv[1], (short)lv[2], (short)lv[3],
                 (short)lv[4], (short)lv[5], (short)lv[6], (short)lv[7]};
    short8 l1 = {(short)lv[8], (short)lv[9], (short)lv[10], (short)lv[11],
                 (short)lv[12], (short)lv[13], (short)lv[14], (short)lv[15]};
    *(short8*)&As[ar][ph * 16] = h0;
    *(short8*)&As[ar][ph * 16 + 8] = h1;
    *(short8*)&Asl[ar][ph * 16] = l0;
    *(short8*)&Asl[ar][ph * 16 + 8] = l1;
    *(short8*)&Bsh[br0][bco] = rb0;
    *(short8*)&Bsh[br1][bco] = rb1;
    *(short8*)&Bsl[br0][bco] = rc0;
    *(short8*)&Bsl[br1][bco] = rc1;
  };

  issue(0);
  commit();
  __syncthreads();

  for (int k0 = 0;;) {
    const bool more = (k0 + 32 < K);
    if (more) issue(k0 + 32);
    short8 af[4], al4[4], bh4[4], bl4[4];
#pragma unroll
    for (int i = 0; i < 4; ++i) {
      af[i] = *(const short8*)&As[wm * 64 + i * 16 + rsel][ksel];
      al4[i] = *(const short8*)&Asl[wm * 64 + i * 16 + rsel][ksel];
    }
#pragma unroll
    for (int j = 0; j < 4; ++j) {
      bh4[j] = *(const short8*)&Bsh[wn * 64 + j * 16 + rsel][ksel];
      bl4[j] = *(const short8*)&Bsl[wn * 64 + j * 16 + rsel][ksel];
    }
#pragma unroll
    for (int i = 0; i < 4; ++i)
#pragma unroll
      for (int j = 0; j < 4; ++j) {
        acc[i][j] = __builtin_amdgcn_mfma_f32_16x16x32_bf16(af[i], bh4[j], acc[i][j], 0, 0, 0);
        acc[i][j] = __builtin_amdgcn_mfma_f32_16x16x32_bf16(al4[i], bh4[j], acc[i][j], 0, 0, 0);
        acc[i][j] = __builtin_amdgcn_mfma_f32_16x16x32_bf16(af[i], bl4[j], acc[i][j], 0, 0, 0);
      }
    k0 += 32;
    if (!more) break;
    __syncthreads();
    commit();
    __syncthreads();
  }

#pragma unroll
  for (int i = 0; i < 4; ++i) {
#pragma unroll
    for (int j = 0; j < 4; ++j) {
#pragma unroll
      for (int r = 0; r < 4; ++r) {
        int grow = row0 + wm * 64 + i * 16 + (lane >> 4) * 4 + r;   // token
        int gcol = col0 + wn * 64 + j * 16 + rsel;                  // feature
        float v = acc[i][j][r] + bias[gcol] + pos[(size_t)(grow % NTOK) * N + gcol];
        outf[(size_t)grow * N + gcol] = v;
      }
    }
  }
}

// ---------------------------------------------------------------------------
// Fused MoE v4 (r12 + rcp-gelu): 64-token tiles, hi-only weights, 80 KB LDS,
// 2 blocks/CU, operand-swapped MFMAs (lane holds consecutive hid/out per tok).
// ---------------------------------------------------------------------------
__global__ __launch_bounds__(512, 4) void moe_fused(
    const u16* __restrict__ x1h,
    const u16* __restrict__ w1, const u16* __restrict__ w2,
    const float* __restrict__ b1, const float* __restrict__ b2,
    const float* __restrict__ gates,
    const int* __restrict__ idx_all, const int* __restrict__ cnt_all,
    const int* __restrict__ base_all,
    float* __restrict__ yslot)
{
  const int e = blockIdx.z;
  const int Meff = cnt_all[e];
  const int row0 = blockIdx.x * 64;
  if (row0 >= Meff) return;
  const int* gidx = idx_all + (size_t)e * T_TOK;
  const int hbase = base_all[e];
  const u16* W1 = w1 + (size_t)e * 262144;   // [1024][256] (n,k)
  const u16* W2 = w2 + (size_t)e * 262144;   // [256][1024] (n,k)
  const float* B1 = b1 + e * 1024;
  const float* B2 = b2 + e * 256;

  __shared__ u16 Xs[64][256];       // 32 KB, SWZ16
  __shared__ u16 Hs[64][128];       // 16 KB, SWZ4 (row-major [tok][hid])
  __shared__ u16 Ws[2 * 128 * 64];  // 32 KB: ph1 dbuf 2x[128][64]; ph2 flat [256][64]

  const int tid = threadIdx.x, lane = tid & 63, wn = tid >> 6;   // 8 waves
  const int rsel = lane & 15, ksel = (lane >> 4) * 8;
  const f32x4 zero = {0.f, 0.f, 0.f, 0.f};

  const int w1r = tid >> 2, w1c = ((2 * tid) & 7) * 8;
  const int w2r = tid >> 1, w2c = ((4 * tid) & 7) * 8;

  short8 w1a = *(const short8*)(W1 + (size_t)w1r * 256 + w1c);
  short8 w1b = *(const short8*)(W1 + (size_t)w1r * 256 + w1c + 8);
  for (int ch = tid; ch < 2048; ch += 512) {
    int r = ch >> 5, c = (ch & 31) * 8;
    int arr = gidx[min(row0 + r, Meff - 1)];
    *(short8*)&Xs[r][SWZ(r, c)] = *(const short8*)(x1h + (size_t)arr * 256 + c);
  }

  f32x4 acc2[2][4];                 // [out-tile][tok-tile]
#pragma unroll
  for (int i = 0; i < 2; ++i)
#pragma unroll
    for (int j = 0; j < 4; ++j) acc2[i][j] = zero;

  f32x4 acc1[4];                    // [tok-tile]

  // ph1 step: A = W1 slab rows (hid), B = X token tiles. st = k-stage (0..3)
  auto ph1 = [&](int st, int buf) {
#pragma unroll
    for (int kk = 0; kk < 2; ++kk) {
      int wrow = wn * 16 + rsel;
      int wc = kk * 32 + ksel;
      short8 wf = *(const short8*)&Ws[buf * 8192 + wrow * 64 + SWZ(wrow, wc)];
      int kglob = st * 64 + kk * 32 + ksel;
#pragma unroll
      for (int tt = 0; tt < 4; ++tt) {
        int xrow = tt * 16 + rsel;
        short8 xf = *(const short8*)&Xs[xrow][SWZ(xrow, kglob)];
        acc1[tt] = __builtin_amdgcn_mfma_f32_16x16x32_bf16(wf, xf, acc1[tt], 0, 0, 0);
      }
    }
  };
  // ph2 step: A = W2 rows (out), B = H token tiles. st = k-half (0/1)
  auto ph2 = [&](int st) {
#pragma unroll
    for (int kk = 0; kk < 2; ++kk) {
      int wc = kk * 32 + ksel;
      short8 wf[2];
#pragma unroll
      for (int ot = 0; ot < 2; ++ot) {
        int wrow = wn * 32 + ot * 16 + rsel;
        wf[ot] = *(const short8*)&Ws[wrow * 64 + SWZ(wrow, wc)];
      }
      int kc = st * 64 + kk * 32 + ksel;
#pragma unroll
      for (int tt = 0; tt < 4; ++tt) {
        int tok = tt * 16 + rsel;
        short4v lo = *(const short4v*)&Hs[tok][SWZ4(tok, kc)];
        short4v hi = *(const short4v*)&Hs[tok][SWZ4(tok, kc + 4)];
        short8 hf = {lo[0], lo[1], lo[2], lo[3], hi[0], hi[1], hi[2], hi[3]};
#pragma unroll
        for (int ot = 0; ot < 2; ++ot)
          acc2[ot][tt] = __builtin_amdgcn_mfma_f32_16x16x32_bf16(wf[ot], hf, acc2[ot][tt], 0, 0, 0);
      }
    }
  };

  for (int hc = 0; hc < 8; ++hc) {
    const u16* W1c = W1 + (size_t)hc * 128 * 256;
    const u16* W2c = W2 + hc * 128;
    // W2 st0 loads (latency hidden under all of phase 1)
    short8 q0 = *(const short8*)(W2c + (size_t)w2r * 1024 + w2c);
    short8 q1 = *(const short8*)(W2c + (size_t)w2r * 1024 + w2c + 8);
    short8 q2 = *(const short8*)(W2c + (size_t)w2r * 1024 + w2c + 16);
    short8 q3 = *(const short8*)(W2c + (size_t)w2r * 1024 + w2c + 24);

#pragma unroll
    for (int i = 0; i < 4; ++i) acc1[i] = zero;

    // ---- phase 1: 4 stages of BK=64, dbuf ----
    *(short8*)&Ws[w1r * 64 + SWZ(w1r, w1c)] = w1a;
    *(short8*)&Ws[w1r * 64 + SWZ(w1r, w1c + 8)] = w1b;
    short8 p0 = *(const short8*)(W1c + (size_t)w1r * 256 + 64 + w1c);
    short8 p1 = *(const short8*)(W1c + (size_t)w1r * 256 + 64 + w1c + 8);
    __syncthreads();                                           // B1
    short8 s0 = *(const short8*)(W1c + (size_t)w1r * 256 + 128 + w1c);
    short8 s1 = *(const short8*)(W1c + (size_t)w1r * 256 + 128 + w1c + 8);
    ph1(0, 0);
    *(short8*)&Ws[8192 + w1r * 64 + SWZ(w1r, w1c)] = p0;
    *(short8*)&Ws[8192 + w1r * 64 + SWZ(w1r, w1c + 8)] = p1;
    __syncthreads();                                           // B2
    p0 = *(const short8*)(W1c + (size_t)w1r * 256 + 192 + w1c);
    p1 = *(const short8*)(W1c + (size_t)w1r * 256 + 192 + w1c + 8);
    ph1(1, 1);
    *(short8*)&Ws[w1r * 64 + SWZ(w1r, w1c)] = s0;
    *(short8*)&Ws[w1r * 64 + SWZ(w1r, w1c + 8)] = s1;
    __syncthreads();                                           // B3
    ph1(2, 0);
    *(short8*)&Ws[8192 + w1r * 64 + SWZ(w1r, w1c)] = p0;
    *(short8*)&Ws[8192 + w1r * 64 + SWZ(w1r, w1c + 8)] = p1;
    __syncthreads();                                           // B4
    ph1(3, 1);

    // ---- gelu -> Hs (packed ushort4, SWZ4; rcp instead of divide) ----
#pragma unroll
    for (int tt = 0; tt < 4; ++tt) {
      int tok = tt * 16 + rsel;
      int hid0 = wn * 16 + (lane >> 4) * 4;
      u16 hv[4];
#pragma unroll
      for (int r = 0; r < 4; ++r) {
        float v = acc1[tt][r] + B1[hc * 128 + hid0 + r];
        float u = 1.5957691216057308f * (v + 0.044715f * v * v * v);
        float sig = __builtin_amdgcn_rcpf(1.f + __expf(-u));
        hv[r] = bfbits(v * sig);
      }
      *(ushort4*)&Hs[tok][SWZ4(tok, hid0)] = make_ushort4(hv[0], hv[1], hv[2], hv[3]);
    }
    __syncthreads();                                           // B5 (Ws free + Hs ready)

    // ---- phase 2: 2 halves of BK=64, Ws reused flat [256][64] ----
    *(short8*)&Ws[w2r * 64 + SWZ(w2r, w2c)] = q0;
    *(short8*)&Ws[w2r * 64 + SWZ(w2r, w2c + 8)] = q1;
    *(short8*)&Ws[w2r * 64 + SWZ(w2r, w2c + 16)] = q2;
    *(short8*)&Ws[w2r * 64 + SWZ(w2r, w2c + 24)] = q3;
    q0 = *(const short8*)(W2c + (size_t)w2r * 1024 + 64 + w2c);
    q1 = *(const short8*)(W2c + (size_t)w2r * 1024 + 64 + w2c + 8);
    q2 = *(const short8*)(W2c + (size_t)w2r * 1024 + 64 + w2c + 16);
    q3 = *(const short8*)(W2c + (size_t)w2r * 1024 + 64 + w2c + 24);
    __syncthreads();                                           // B6
    ph2(0);
    __syncthreads();                                           // B7
    *(short8*)&Ws[w2r * 64 + SWZ(w2r, w2c)] = q0;
    *(short8*)&Ws[w2r * 64 + SWZ(w2r, w2c + 8)] = q1;
    *(short8*)&Ws[w2r * 64 + SWZ(w2r, w2c + 16)] = q2;
    *(short8*)&Ws[w2r * 64 + SWZ(w2r, w2c + 24)] = q3;
    if (hc < 7) {   // next-hc W1 st0 loads hide under phase-2 st1
      w1a = *(const short8*)(W1 + (size_t)((hc + 1) * 128 + w1r) * 256 + w1c);
      w1b = *(const short8*)(W1 + (size_t)((hc + 1) * 128 + w1r) * 256 + w1c + 8);
    }
    __syncthreads();                                           // B8
    ph2(1);
    __syncthreads();                                           // B9 (Ws+Hs free)
  }

  // ---- epilogue: yslot = gate * (Y + b2), float4 full-line stores ----
#pragma unroll
  for (int tt = 0; tt < 4; ++tt) {
    int grow = row0 + tt * 16 + rsel;
    if (grow < Meff) {
      int tk = gidx[grow];
      float gt = gates[(size_t)tk * 6 + e];
#pragma unroll
      for (int ot = 0; ot < 2; ++ot) {
        int out0 = wn * 32 + ot * 16 + (lane >> 4) * 4;
        float4 w4 = make_float4(gt * (acc2[ot][tt][0] + B2[out0]),
                                gt * (acc2[ot][tt][1] + B2[out0 + 1]),
                                gt * (acc2[ot][tt][2] + B2[out0 + 2]),
                                gt * (acc2[ot][tt][3] + B2[out0 + 3]));
        *(float4*)&yslot[(size_t)(hbase + grow) * 256 + out0] = w4;
      }
    }
  }
}

// ---------------------------------------------------------------------------
// LayerNorm over E=256: wave per token; bf16 out
// ---------------------------------------------------------------------------
__global__ __launch_bounds__(256) void ln_kernel(const float* __restrict__ in,
    const float* __restrict__ g, const float* __restrict__ b, u16* __restrict__ oh)
{
  const int lane = threadIdx.x & 63;
  const int t = blockIdx.x * 4 + (threadIdx.x >> 6);
  const float4 v = *(const float4*)(in + (size_t)t * 256 + lane * 4);
  float s = v.x + v.y + v.z + v.w;
  float sq = v.x * v.x + v.y * v.y + v.z * v.z + v.w * v.w;
#pragma unroll
  for (int o = 32; o >= 1; o >>= 1) {
    s  += __shfl_xor(s,  o, 64);
    sq += __shfl_xor(sq, o, 64);
  }
  float mu = s * (1.f / 256.f);
  float var = sq * (1.f / 256.f) - mu * mu;
  float rstd = rsqrtf(var + 1e-5f);
  const float4 gv = *(const float4*)(g + lane * 4);
  const float4 bv = *(const float4*)(b + lane * 4);
  *(ushort4*)(oh + (size_t)t * 256 + lane * 4) = make_ushort4(
      bfbits((v.x - mu) * rstd * gv.x + bv.x), bfbits((v.y - mu) * rstd * gv.y + bv.y),
      bfbits((v.z - mu) * rstd * gv.z + bv.z), bfbits((v.w - mu) * rstd * gv.w + bv.w));
}

// ---------------------------------------------------------------------------
// Fused slot-combine + LayerNorm: moe[t] = yslot[s0]+yslot[s1]; x2 = LN(moe)
// ---------------------------------------------------------------------------
__global__ __launch_bounds__(256) void ln2_combine(const float* __restrict__ yslot,
    const int* __restrict__ invslot,
    const float* __restrict__ g, const float* __restrict__ b, float* __restrict__ outf)
{
  const int lane = threadIdx.x & 63;
  const int t = blockIdx.x * 4 + (threadIdx.x >> 6);
  const int s0 = invslot[t * 2], s1 = invslot[t * 2 + 1];
  const float4 a = *(const float4*)(yslot + (size_t)s0 * 256 + lane * 4);
  const float4 c = *(const float4*)(yslot + (size_t)s1 * 256 + lane * 4);
  float4 v = make_float4(a.x + c.x, a.y + c.y, a.z + c.z, a.w + c.w);
  float s = v.x + v.y + v.z + v.w;
  float sq = v.x * v.x + v.y * v.y + v.z * v.z + v.w * v.w;
#pragma unroll
  for (int o = 32; o >= 1; o >>= 1) {
    s  += __shfl_xor(s,  o, 64);
    sq += __shfl_xor(sq, o, 64);
  }
  float mu = s * (1.f / 256.f);
  float var = sq * (1.f / 256.f) - mu * mu;
  float rstd = rsqrtf(var + 1e-5f);
  const float4 gv = *(const float4*)(g + lane * 4);
  const float4 bv = *(const float4*)(b + lane * 4);
  *(float4*)(outf + (size_t)t * 256 + lane * 4) = make_float4(
      (v.x - mu) * rstd * gv.x + bv.x, (v.y - mu) * rstd * gv.y + bv.y,
      (v.z - mu) * rstd * gv.z + bv.z, (v.w - mu) * rstd * gv.w + bv.w);
}

// ---------------------------------------------------------------------------
// MFMA attention: one block per (b,h), 4 waves, 13 m-tiles of 16 q-rows.
// ao written split (hi+lo): feeds wo -> x1f -> router (gate precision).
// ---------------------------------------------------------------------------
__global__ __launch_bounds__(256) void attn_mfma(const u16* __restrict__ qkvb,
                                                 u16* __restrict__ aoh, u16* __restrict__ aol) {
  __shared__ u16 Qs[208][40];
  __shared__ u16 Ks[208][40];
  __shared__ u16 Vt[32][256];
  __shared__ u16 Ps[4][16][232];
  const int tid = threadIdx.x, lane = tid & 63, wave = tid >> 6;
  const int b = blockIdx.x >> 3, h = blockIdx.x & 7;
  const size_t base = (size_t)b * 196 * 768 + h * 32;
  const short8 z8 = {0, 0, 0, 0, 0, 0, 0, 0};

  for (int idx = tid; idx < 832; idx += 256) {
    int r = idx >> 2, c = (idx & 3) * 8;
    short8 q = z8, k = z8;
    if (r < 196) {
      q = *(const short8*)(qkvb + base + (size_t)r * 768 + c);
      k = *(const short8*)(qkvb + base + (size_t)r * 768 + 256 + c);
    }
    *(short8*)&Qs[r][c] = q;
    *(short8*)&Ks[r][c] = k;
  }
  for (int idx = tid; idx < 32 * 224; idx += 256) {
    int c = idx & 31, k = idx >> 5;
    u16 v = 0;
    if (k < 196) v = qkvb[base + (size_t)k * 768 + 512 + c];
    Vt[c][k ^ ((c & 7) << 3)] = v;
  }
  {
    int r = lane >> 2, c0 = 208 + (lane & 3) * 4;
    Ps[wave][r][c0] = 0; Ps[wave][r][c0 + 1] = 0; Ps[wave][r][c0 + 2] = 0; Ps[wave][r][c0 + 3] = 0;
  }
  __syncthreads();

  const int rsel = lane & 15, ksel = (lane >> 4) * 8;
  const f32x4 zero = {0.f, 0.f, 0.f, 0.f};

  for (int mt = wave; mt < 13; mt += 4) {
    short8 aq = *(const short8*)&Qs[mt * 16 + rsel][ksel];
    f32x4 sacc[13];
#pragma unroll
    for (int n = 0; n < 13; ++n)
      sacc[n] = __builtin_amdgcn_mfma_f32_16x16x32_bf16(
          aq, *(const short8*)&Ks[n * 16 + rsel][ksel], zero, 0, 0, 0);

#pragma unroll
    for (int r = 0; r < 4; ++r) {
      float mv = -1e30f;
#pragma unroll
      for (int n = 0; n < 13; ++n) {
        float sv = sacc[n][r] * 0.17677669529663687f;
        sacc[n][r] = sv;
        if (n * 16 + rsel < 196) mv = fmaxf(mv, sv);
      }
      mv = fmaxf(mv, __shfl_xor(mv, 1, 64));
      mv = fmaxf(mv, __shfl_xor(mv, 2, 64));
      mv = fmaxf(mv, __shfl_xor(mv, 4, 64));
      mv = fmaxf(mv, __shfl_xor(mv, 8, 64));
      float sm = 0.f;
#pragma unroll
      for (int n = 0; n < 13; ++n) {
        float p = (n * 16 + rsel < 196) ? __expf(sacc[n][r] - mv) : 0.f;
        sacc[n][r] = p;
        sm += p;
      }
      sm += __shfl_xor(sm, 1, 64);
      sm += __shfl_xor(sm, 2, 64);
      sm += __shfl_xor(sm, 4, 64);
      sm += __shfl_xor(sm, 8, 64);
      float inv = 1.f / sm;
      int prow = (lane >> 4) * 4 + r;
#pragma unroll
      for (int n = 0; n < 13; ++n)
        Ps[wave][prow][n * 16 + rsel] = bfbits(sacc[n][r] * inv);
    }

    f32x4 oacc[2] = {zero, zero};
#pragma unroll
    for (int kk = 0; kk < 7; ++kk) {
      short8 ap = *(const short8*)&Ps[wave][rsel][kk * 32 + ksel];
#pragma unroll
      for (int nt = 0; nt < 2; ++nt) {
        int d = nt * 16 + rsel;
        short8 bv = *(const short8*)&Vt[d][(kk * 32 + ksel) ^ ((d & 7) << 3)];
        oacc[nt] = __builtin_amdgcn_mfma_f32_16x16x32_bf16(ap, bv, oacc[nt], 0, 0, 0);
      }
    }
#pragma unroll
    for (int nt = 0; nt < 2; ++nt) {
#pragma unroll
      for (int r = 0; r < 4; ++r) {
        int row = mt * 16 + (lane >> 4) * 4 + r;
        if (row < 196) {
          size_t oi = ((size_t)b * 196 + row) * 256 + h * 32 + nt * 16 + rsel;
          u16 hh, ll; fsplit(oacc[nt][r], hh, ll);
          aoh[oi] = hh; aol[oi] = ll;
        }
      }
    }
  }
}

// ---------------------------------------------------------------------------
// Router: wave per token; 6 logits, softmax, top-2 -> dense gates [T,6]
// ---------------------------------------------------------------------------
__global__ __launch_bounds__(256) void router_kernel(const float* __restrict__ x1,
    const float* __restrict__ rw, const float* __restrict__ rb, float* __restrict__ gates)
{
  const int lane = threadIdx.x & 63;
  const int t = blockIdx.x * 4 + (threadIdx.x >> 6);
  const float4 xv = *(const float4*)(x1 + (size_t)t * 256 + lane * 4);
  float logit[6];
#pragma unroll
  for (int e = 0; e < 6; ++e) {
    const float4 wv = *(const float4*)(rw + e * 256 + lane * 4);
    float p = xv.x * wv.x + xv.y * wv.y + xv.z * wv.z + xv.w * wv.w;
#pragma unroll
    for (int o = 32; o >= 1; o >>= 1) p += __shfl_xor(p, o, 64);
    logit[e] = p + rb[e];
  }
  float mx = logit[0];
#pragma unroll
  for (int e = 1; e < 6; ++e) mx = fmaxf(mx, logit[e]);
  float pe[6], sum = 0.f;
#pragma unroll
  for (int e = 0; e < 6; ++e) { pe[e] = __expf(logit[e] - mx); sum += pe[e]; }
  float inv = 1.f / sum;
  int i1 = 0; float p1 = pe[0];
#pragma unroll
  for (int e = 1; e < 6; ++e) if (pe[e] > p1) { p1 = pe[e]; i1 = e; }
  int i2 = -1; float p2 = -1.f;
#pragma unroll
  for (int e = 0; e < 6; ++e) if (e != i1 && pe[e] > p2) { p2 = pe[e]; i2 = e; }
  if (lane < 6)
    gates[(size_t)t * 6 + lane] = (lane == i1) ? p1 * inv : ((lane == i2) ? p2 * inv : 0.f);
}

// ---------------------------------------------------------------------------
// Scatter: build per-expert token lists (block-aggregated atomics)
// ---------------------------------------------------------------------------
__global__ __launch_bounds__(256) void scatter_kernel(const float* __restrict__ gates,
                                                      int* __restrict__ cnt, int* __restrict__ idx) {
  __shared__ int lcnt[6], lbase[6];
  const int t = blockIdx.x * 256 + threadIdx.x;
  if (threadIdx.x < 6) lcnt[threadIdx.x] = 0;
  __syncthreads();
  float g[6]; int lpos[6];
#pragma unroll
  for (int e = 0; e < 6; ++e) {
    g[e] = gates[(size_t)t * 6 + e];
    if (g[e] > 0.f) lpos[e] = atomicAdd(&lcnt[e], 1);
  }
  __syncthreads();
  if (threadIdx.x < 6) lbase[threadIdx.x] = atomicAdd(&cnt[threadIdx.x], lcnt[threadIdx.x]);
  __syncthreads();
#pragma unroll
  for (int e = 0; e < 6; ++e)
    if (g[e] > 0.f) idx[(size_t)e * T_TOK + lbase[e] + lpos[e]] = t;
}

// exclusive prefix over the 6 expert counts -> segment bases in slot buffer
__global__ void prefix6_kernel(const int* __restrict__ cnt, int* __restrict__ base) {
  if (threadIdx.x == 0) {
    int s = 0;
#pragma unroll
    for (int e = 0; e < 6; ++e) { base[e] = s; s += cnt[e]; }
  }
}

// token -> its 2 slot positions in the concatenated expert segments
__global__ __launch_bounds__(256) void slotmap_kernel(const int* __restrict__ idx,
    const int* __restrict__ cnt, const int* __restrict__ base,
    int* __restrict__ nslot, int* __restrict__ invslot) {
  const int e = blockIdx.y;
  const int p = blockIdx.x * 256 + threadIdx.x;
  if (p < cnt[e]) {
    int t = idx[(size_t)e * T_TOK + p];
    int j = atomicAdd(&nslot[t], 1);
    invslot[(size_t)t * 2 + j] = base[e] + p;
  }
}

// ---------------------------------------------------------------------------
// Mean-pool over tokens (fp32)
// ---------------------------------------------------------------------------
__global__ __launch_bounds__(256) void pool_kernel(const float* __restrict__ x2, float* __restrict__ pooled) {
  int b = blockIdx.x, e = threadIdx.x;
  float s = 0.f;
  for (int n = 0; n < 196; ++n) s += x2[((size_t)b * 196 + n) * 256 + e];
  pooled[(size_t)b * 256 + e] = s * (1.f / 196.f);
}

// ---------------------------------------------------------------------------
// Head v2: 32 blocks x 32 classes; pooled[128][256] staged once in LDS,
// hw read exactly once chip-wide. Same fp32 accumulation order per dot.
// ---------------------------------------------------------------------------
__global__ __launch_bounds__(256) void head_kernel(const float* __restrict__ pooled,
    const float* __restrict__ hw, const float* __restrict__ hb, float* __restrict__ out) {
  __shared__ float p[128][257];       // +1 pad
  const int tid = threadIdx.x;
  const int c0 = blockIdx.x * 32;
  for (int i = tid; i < 8192; i += 256) {   // 8192 float4 = 32768 floats
    int b = i >> 6, f = (i & 63) * 4;
    float4 v = *(const float4*)(pooled + (size_t)b * 256 + f);
    p[b][f] = v.x; p[b][f + 1] = v.y; p[b][f + 2] = v.z; p[b][f + 3] = v.w;
  }
  __syncthreads();
  const int cls = c0 + (tid & 31);
  const int b0 = (tid >> 5) * 16;           // 8 groups x 16 batches
  if (cls < 1000) {
    const float* w = hw + (size_t)cls * 256;
    const float bias = hb[cls];
    float acc[16];
#pragma unroll
    for (int j = 0; j < 16; ++j) acc[j] = bias;
    for (int k = 0; k < 256; k += 4) {
      float4 wv = *(const float4*)(w + k);
#pragma unroll
      for (int j = 0; j < 16; ++j)
        acc[j] += p[b0 + j][k] * wv.x + p[b0 + j][k + 1] * wv.y +
                  p[b0 + j][k + 2] * wv.z + p[b0 + j][k + 3] * wv.w;
    }
#pragma unroll
    for (int j = 0; j < 16; ++j)
      out[(size_t)(b0 + j) * 1000 + cls] = acc[j];
  }
}

// ---------------------------------------------------------------------------
// Weight prep: f32 -> hi/lo bf16 split; transpose+cast (hi-only) for MoE
// ---------------------------------------------------------------------------
__global__ void cast_split_kernel(const float* __restrict__ in,
                                  u16* __restrict__ oh, u16* __restrict__ ol, int n4) {
  int id = blockIdx.x * 256 + threadIdx.x;
  if (id >= n4) return;
  float4 v = ((const float4*)in)[id];
  u16 h0, l0, h1, l1, h2, l2, h3, l3;
  fsplit(v.x, h0, l0); fsplit(v.y, h1, l1); fsplit(v.z, h2, l2); fsplit(v.w, h3, l3);
  ((ushort4*)oh)[id] = make_ushort4(h0, h1, h2, h3);
  ((ushort4*)ol)[id] = make_ushort4(l0, l1, l2, l3);
}

__global__ __launch_bounds__(256) void transpose_cast(const float* __restrict__ in,
    u16* __restrict__ oh, int R, int C) {
  __shared__ float tile[32][33];
  const int e = blockIdx.z;
  const int bc = blockIdx.x * 32, br = blockIdx.y * 32;
  const int tx = threadIdx.x & 31, ty = threadIdx.x >> 5;
  const float* src = in + (size_t)e * R * C;
#pragma unroll
  for (int i = 0; i < 32; i += 8)
    tile[ty + i][tx] = src[(size_t)(br + ty + i) * C + bc + tx];
  __syncthreads();
#pragma unroll
  for (int i = 0; i < 32; i += 8) {
    size_t di = (size_t)e * R * C + (size_t)(bc + ty + i) * R + br + tx;
    oh[di] = bfbits(tile[tx][ty + i]);
  }
}

// ---------------------------------------------------------------------------
extern "C" void kernel_launch(void* const* d_in, const int* in_sizes, int n_in,
                              void* d_out, int out_size, void* d_ws, size_t ws_size,
                              hipStream_t stream) {
  (void)in_sizes; (void)n_in; (void)out_size; (void)ws_size;
  const float* x      = (const float*)d_in[0];
  const float* conv_w = (const float*)d_in[1];
  const float* conv_b = (const float*)d_in[2];
  const float* pos    = (const float*)d_in[3];
  const float* ln1_g  = (const float*)d_in[4];
  const float* ln1_b  = (const float*)d_in[5];
  const float* wqkv   = (const float*)d_in[6];
  const float* bqkv   = (const float*)d_in[7];
  const float* wo     = (const float*)d_in[8];
  const float* bo     = (const float*)d_in[9];
  const float* rw     = (const float*)d_in[10];
  const float* rb     = (const float*)d_in[11];
  const float* w1     = (const float*)d_in[12];
  const float* b1     = (const float*)d_in[13];
  const float* w2     = (const float*)d_in[14];
  const float* b2     = (const float*)d_in[15];
  const float* ln2_g  = (const float*)d_in[16];
  const float* ln2_b  = (const float*)d_in[17];
  const float* hw     = (const float*)d_in[18];
  const float* hb     = (const float*)d_in[19];
  float* out = (float*)d_out;

  const int T = T_TOK;
  char* ws = (char*)d_ws;
  size_t off = 0;
  auto alloc = [&](size_t bytes) -> void* {
    void* p = ws + off;
    off += (bytes + 255) & ~(size_t)255;
    return p;
  };
  // region 0: tok+xnh+qkvb -> reused as x2 after qkv consumed
  float* tok    = (float*)alloc((size_t)T * 256 * 4);
  u16*   xnh    = (u16*)  alloc((size_t)T * 256 * 2);
  u16*   qkvb   = (u16*)  alloc((size_t)T * 768 * 2);
  // region 1: aoh+aol+x1f == exactly [2T,256] f32 -> reused as yslot
  u16*   aoh    = (u16*)  alloc((size_t)T * 256 * 2);
  u16*   aol    = (u16*)  alloc((size_t)T * 256 * 2);
  float* x1f    = (float*)alloc((size_t)T * 256 * 4);
  u16*   x1h    = (u16*)  alloc((size_t)T * 256 * 2);
  float* gates  = (float*)alloc((size_t)T * 6 * 4);
  int*   idx    = (int*)  alloc((size_t)6 * T * 4);
  int*   cnt    = (int*)  alloc(256);
  int*   base   = (int*)  alloc(256);
  int*   nslot  = (int*)  alloc((size_t)T * 4);
  int*   invslot= (int*)  alloc((size_t)2 * T * 4);
  float* pooled = (float*)alloc((size_t)128 * 256 * 4);
  u16*   cwh    = (u16*)  alloc((size_t)196608 * 2);
  u16*   cwl    = (u16*)  alloc((size_t)196608 * 2);
  u16*   wqh    = (u16*)  alloc((size_t)196608 * 2);
  u16*   wql    = (u16*)  alloc((size_t)196608 * 2);
  u16*   woh    = (u16*)  alloc((size_t)65536 * 2);
  u16*   wol    = (u16*)  alloc((size_t)65536 * 2);
  u16*   w1th   = (u16*)  alloc((size_t)6 * 262144 * 2);
  u16*   w2th   = (u16*)  alloc((size_t)6 * 262144 * 2);
  // aliases (lifetimes disjoint):
  float* yslot = (float*)aoh;   // [2T,256] f32 (region 1; exact fit)
  float* x2    = (float*)ws;    // [T,256] f32 (region 0 head; tok dead by then)

  // --- weight prep (router-path weights hi+lo; MoE weights hi-only) ---
  cast_split_kernel<<<192, 256, 0, stream>>>(conv_w, cwh, cwl, 49152);
  cast_split_kernel<<<192, 256, 0, stream>>>(wqkv, wqh, wql, 49152);
  cast_split_kernel<<<64, 256, 0, stream>>>(wo, woh, wol, 16384);
  transpose_cast<<<dim3(32, 8, 6), 256, 0, stream>>>(w1, w1th, 256, 1024);  // [e][n][k]
  transpose_cast<<<dim3(8, 32, 6), 256, 0, stream>>>(w2, w2th, 1024, 256);  // [e][n][k]

  // --- patch embedding (fused im2col + split-A GEMM) ---
  gemm_patch<<<dim3(196, 2), 256, 0, stream>>>(x, cwh, cwl, conv_b, pos, tok);

  // --- attention block ---
  ln_kernel<<<6272, 256, 0, stream>>>(tok, ln1_g, ln1_b, xnh);
  gemm_bs<5, false><<<dim3(196, 6), 256, 0, stream>>>(xnh, nullptr, wqh, wql, T, 768, 256,
      bqkv, nullptr, nullptr, qkvb);
  attn_mfma<<<1024, 256, 0, stream>>>(qkvb, aoh, aol);
  gemm_bs<2, true><<<dim3(196, 2), 256, 0, stream>>>(aoh, aol, woh, wol, T, 256, 256,
      bo, tok, x1f, x1h);

  // --- MoE (top-2 sparse, fused GEMM1+gelu+GEMM2, 2 blocks/CU) ---
  router_kernel<<<6272, 256, 0, stream>>>(x1f, rw, rb, gates);
  hipMemsetAsync(cnt, 0, 256, stream);
  scatter_kernel<<<98, 256, 0, stream>>>(gates, cnt, idx);
  prefix6_kernel<<<1, 64, 0, stream>>>(cnt, base);
  hipMemsetAsync(nslot, 0, (size_t)T * 4, stream);
  slotmap_kernel<<<dim3(98, 6), 256, 0, stream>>>(idx, cnt, base, nslot, invslot);
  moe_fused<<<dim3(392, 1, 6), 512, 0, stream>>>(x1h, w1th, w2th,
      b1, b2, gates, idx, cnt, base, yslot);

  // --- final norm (fused slot combine), pool, head ---
  ln2_combine<<<6272, 256, 0, stream>>>(yslot, invslot, ln2_g, ln2_b, x2);
  pool_kernel<<<128, 256, 0, stream>>>(x2, pooled);
  head_kernel<<<32, 256, 0, stream>>>(pooled, hw, hb, out);
}

// Round 18
// 381.624 us; speedup vs baseline: 1.0611x; 1.0009x over previous
//
#include <hip/hip_runtime.h>
#include <hip/hip_bf16.h>

typedef unsigned short u16;
typedef short short8 __attribute__((ext_vector_type(8)));
typedef short short4v __attribute__((ext_vector_type(4)));
typedef float f32x4 __attribute__((ext_vector_type(4)));

#define T_TOK 25088   // 128*196
#define NTOK 196
// 16B-chunk XOR swizzle (T2-style)
#define SWZ(r, c) ((((((c) >> 3) ^ ((r) & 7)) << 3)) | ((c) & 7))
// 8B-chunk XOR swizzle (for Hs: packed ushort4 writes + paired b64 reads)
#define SWZ4(r, c) ((((((c) >> 2) & 16) | ((((c) >> 2) ^ (r)) & 15)) << 2) | ((c) & 3))

__device__ __forceinline__ u16 bfbits(float v) {
  __hip_bfloat16 h = __float2bfloat16(v);
  return *reinterpret_cast<u16*>(&h);
}
__device__ __forceinline__ float b2f(u16 u) {
  __hip_bfloat16 h = *reinterpret_cast<__hip_bfloat16*>(&u);
  return __bfloat162float(h);
}
// near-fp32 as hi+lo bf16 pair (Ootomo split)
__device__ __forceinline__ void fsplit(float v, u16& hi, u16& lo) {
  hi = bfbits(v);
  lo = bfbits(v - b2f(hi));
}

// ---------------------------------------------------------------------------
// Dense GEMM: C[M,N] = A[M,K] @ (Bh+Bl)[N,K]^T + bias.
// A split (hi+lo, 3 MFMA/frag) when SPLITA — router-input path (wo).
// ALL weight lo-terms are load-bearing (r6/r17 lesson: weight quantization is
// token-correlated -> router gate flips). 128x128 tile, BK=32, 4 waves.
// EPI: 2 +resid->f32+bf16 | 5 ->bf16
// ---------------------------------------------------------------------------
template<int EPI, bool SPLITA>
__global__ __launch_bounds__(256) void gemm_bs(
    const u16* __restrict__ A, const u16* __restrict__ Al,
    const u16* __restrict__ Bh, const u16* __restrict__ Bl,
    int M, int N, int K,
    const float* __restrict__ bias, const float* __restrict__ extra,
    float* __restrict__ outf, u16* __restrict__ obh)
{
  __shared__ u16 As[128][40];                      // +8 pad: 2-way banks
  __shared__ u16 Asl[SPLITA ? 128 : 1][40];
  __shared__ u16 Bsh[128][40], Bsl[128][40];
  const int tid = threadIdx.x;
  const int lane = tid & 63, wave = tid >> 6;
  const int wm = wave >> 1, wn = wave & 1;
  const int row0 = blockIdx.x * 128, col0 = blockIdx.y * 128;

  const int r0 = tid >> 2, r1 = r0 + 64, co = (tid & 3) * 8;
  const int ar0 = row0 + r0, ar1 = row0 + r1;

  f32x4 acc[4][4];
  const f32x4 zero = {0.f, 0.f, 0.f, 0.f};
#pragma unroll
  for (int i = 0; i < 4; ++i)
#pragma unroll
    for (int j = 0; j < 4; ++j) acc[i][j] = zero;

  const int rsel = lane & 15, ksel = (lane >> 4) * 8;

  short8 ra, rl, rb0, rb1, rc0, rc1;
  auto issue = [&](int k0) {
    ra = *(const short8*)(A + (size_t)ar0 * K + k0 + co);
    rl = *(const short8*)(A + (size_t)ar1 * K + k0 + co);
    rb0 = *(const short8*)(Bh + (size_t)(col0 + r0) * K + k0 + co);
    rb1 = *(const short8*)(Bh + (size_t)(col0 + r1) * K + k0 + co);
    rc0 = *(const short8*)(Bl + (size_t)(col0 + r0) * K + k0 + co);
    rc1 = *(const short8*)(Bl + (size_t)(col0 + r1) * K + k0 + co);
  };
  short8 sa, sl;
  auto issueS = [&](int k0) {
    if constexpr (SPLITA) {
      sa = *(const short8*)(Al + (size_t)ar0 * K + k0 + co);
      sl = *(const short8*)(Al + (size_t)ar1 * K + k0 + co);
    }
  };
  auto commit = [&]() {
    *(short8*)&As[r0][co] = ra;
    *(short8*)&As[r1][co] = rl;
    if constexpr (SPLITA) {
      *(short8*)&Asl[r0][co] = sa;
      *(short8*)&Asl[r1][co] = sl;
    }
    *(short8*)&Bsh[r0][co] = rb0;
    *(short8*)&Bsh[r1][co] = rb1;
    *(short8*)&Bsl[r0][co] = rc0;
    *(short8*)&Bsl[r1][co] = rc1;
  };

  issue(0);
  issueS(0);
  commit();
  __syncthreads();

  for (int k0 = 0;;) {
    const bool more = (k0 + 32 < K);
    if (more) { issue(k0 + 32); issueS(k0 + 32); }
    short8 af[4], al4[4], bh4[4], bl4[4];
#pragma unroll
    for (int i = 0; i < 4; ++i) {
      af[i] = *(const short8*)&As[wm * 64 + i * 16 + rsel][ksel];
      if constexpr (SPLITA) al4[i] = *(const short8*)&Asl[wm * 64 + i * 16 + rsel][ksel];
    }
#pragma unroll
    for (int j = 0; j < 4; ++j) {
      bh4[j] = *(const short8*)&Bsh[wn * 64 + j * 16 + rsel][ksel];
      bl4[j] = *(const short8*)&Bsl[wn * 64 + j * 16 + rsel][ksel];
    }
#pragma unroll
    for (int i = 0; i < 4; ++i)
#pragma unroll
      for (int j = 0; j < 4; ++j) {
        acc[i][j] = __builtin_amdgcn_mfma_f32_16x16x32_bf16(af[i], bh4[j], acc[i][j], 0, 0, 0);
        if constexpr (SPLITA)
          acc[i][j] = __builtin_amdgcn_mfma_f32_16x16x32_bf16(al4[i], bh4[j], acc[i][j], 0, 0, 0);
        acc[i][j] = __builtin_amdgcn_mfma_f32_16x16x32_bf16(af[i], bl4[j], acc[i][j], 0, 0, 0);
      }
    k0 += 32;
    if (!more) break;
    __syncthreads();
    commit();
    __syncthreads();
  }

#pragma unroll
  for (int i = 0; i < 4; ++i) {
#pragma unroll
    for (int j = 0; j < 4; ++j) {
#pragma unroll
      for (int r = 0; r < 4; ++r) {
        int grow = row0 + wm * 64 + i * 16 + (lane >> 4) * 4 + r;   // token
        int gcol = col0 + wn * 64 + j * 16 + rsel;                  // feature
        float v = acc[i][j][r] + bias[gcol];
        size_t oi = (size_t)grow * N + gcol;
        if constexpr (EPI == 2) {
          v += extra[oi];                                  // residual
          outf[oi] = v;
          obh[oi] = bfbits(v);
        } else if constexpr (EPI == 5) {
          obh[oi] = bfbits(v);
        }
      }
    }
  }
}

// ---------------------------------------------------------------------------
// Patch-embed GEMM with FUSED im2col: C[T,256] = A[T,768] @ convW^T + b + pos,
// where A rows are computed from x[B,3,224,224] on the fly (hi/lo split in
// LDS). k = c*256 + p*16 + q; a BK=32 step = one channel c, rows p, p+1.
// ---------------------------------------------------------------------------
__global__ __launch_bounds__(256) void gemm_patch(
    const float* __restrict__ xin,
    const u16* __restrict__ Bh, const u16* __restrict__ Bl,
    const float* __restrict__ bias, const float* __restrict__ pos,
    float* __restrict__ outf)
{
  __shared__ u16 As[128][40], Asl[128][40];
  __shared__ u16 Bsh[128][40], Bsl[128][40];
  const int tid = threadIdx.x;
  const int lane = tid & 63, wave = tid >> 6;
  const int wm = wave >> 1, wn = wave & 1;
  const int row0 = blockIdx.x * 128, col0 = blockIdx.y * 128;
  const int rsel = lane & 15, ksel = (lane >> 4) * 8;
  const int K = 768, N = 256;

  const int ar = tid >> 1, ph = tid & 1;
  const float* srcbase;
  {
    int t = row0 + ar;
    int b = t / 196, n = t - b * 196;
    int gh = n / 14, gw = n - gh * 14;
    srcbase = xin + ((size_t)(b * 3) * 224 + gh * 16) * 224 + gw * 16;
  }
  const int br0 = tid >> 2, br1 = br0 + 64, bco = (tid & 3) * 8;

  f32x4 acc[4][4];
  const f32x4 zero = {0.f, 0.f, 0.f, 0.f};
#pragma unroll
  for (int i = 0; i < 4; ++i)
#pragma unroll
    for (int j = 0; j < 4; ++j) acc[i][j] = zero;

  float4 fa0, fa1, fa2, fa3;           // A prefetch (16 floats)
  short8 rb0, rb1, rc0, rc1;           // B prefetch
  auto issue = [&](int k0) {
    int c = k0 >> 8, p = ((k0 >> 4) & 15) + ph;
    const float* s = srcbase + ((size_t)c * 224 + p) * 224;
    fa0 = *(const float4*)(s);
    fa1 = *(const float4*)(s + 4);
    fa2 = *(const float4*)(s + 8);
    fa3 = *(const float4*)(s + 12);
    rb0 = *(const short8*)(Bh + (size_t)(col0 + br0) * K + k0 + bco);
    rb1 = *(const short8*)(Bh + (size_t)(col0 + br1) * K + k0 + bco);
    rc0 = *(const short8*)(Bl + (size_t)(col0 + br0) * K + k0 + bco);
    rc1 = *(const short8*)(Bl + (size_t)(col0 + br1) * K + k0 + bco);
  };
  auto commit = [&]() {
    float f[16] = {fa0.x, fa0.y, fa0.z, fa0.w, fa1.x, fa1.y, fa1.z, fa1.w,
                   fa2.x, fa2.y, fa2.z, fa2.w, fa3.x, fa3.y, fa3.z, fa3.w};
    u16 hv[16], lv[16];
#pragma unroll
    for (int j = 0; j < 16; ++j) fsplit(f[j], hv[j], lv[j]);
    short8 h0 = {(short)hv[0], (short)hv[1], (short)hv[2], (short)hv[3],
                 (short)hv[4], (short)hv[5], (short)hv[6], (short)hv[7]};
    short8 h1 = {(short)hv[8], (short)hv[9], (short)hv[10], (short)hv[11],
                 (short)hv[12], (short)hv[13], (short)hv[14], (short)hv[15]};
    short8 l0 = {(short)lv[0], (short)lv[1], (short)lv[2], (short)lv[3],
                 (short)lv[4], (short)lv[5], (short)lv[6], (short)lv[7]};
    short8 l1 = {(short)lv[8], (short)lv[9], (short)lv[10], (short)lv[11],
                 (short)lv[12], (short)lv[13], (short)lv[14], (short)lv[15]};
    *(short8*)&As[ar][ph * 16] = h0;
    *(short8*)&As[ar][ph * 16 + 8] = h1;
    *(short8*)&Asl[ar][ph * 16] = l0;
    *(short8*)&Asl[ar][ph * 16 + 8] = l1;
    *(short8*)&Bsh[br0][bco] = rb0;
    *(short8*)&Bsh[br1][bco] = rb1;
    *(short8*)&Bsl[br0][bco] = rc0;
    *(short8*)&Bsl[br1][bco] = rc1;
  };

  issue(0);
  commit();
  __syncthreads();

  for (int k0 = 0;;) {
    const bool more = (k0 + 32 < K);
    if (more) issue(k0 + 32);
    short8 af[4], al4[4], bh4[4], bl4[4];
#pragma unroll
    for (int i = 0; i < 4; ++i) {
      af[i] = *(const short8*)&As[wm * 64 + i * 16 + rsel][ksel];
      al4[i] = *(const short8*)&Asl[wm * 64 + i * 16 + rsel][ksel];
    }
#pragma unroll
    for (int j = 0; j < 4; ++j) {
      bh4[j] = *(const short8*)&Bsh[wn * 64 + j * 16 + rsel][ksel];
      bl4[j] = *(const short8*)&Bsl[wn * 64 + j * 16 + rsel][ksel];
    }
#pragma unroll
    for (int i = 0; i < 4; ++i)
#pragma unroll
      for (int j = 0; j < 4; ++j) {
        acc[i][j] = __builtin_amdgcn_mfma_f32_16x16x32_bf16(af[i], bh4[j], acc[i][j], 0, 0, 0);
        acc[i][j] = __builtin_amdgcn_mfma_f32_16x16x32_bf16(al4[i], bh4[j], acc[i][j], 0, 0, 0);
        acc[i][j] = __builtin_amdgcn_mfma_f32_16x16x32_bf16(af[i], bl4[j], acc[i][j], 0, 0, 0);
      }
    k0 += 32;
    if (!more) break;
    __syncthreads();
    commit();
    __syncthreads();
  }

#pragma unroll
  for (int i = 0; i < 4; ++i) {
#pragma unroll
    for (int j = 0; j < 4; ++j) {
#pragma unroll
      for (int r = 0; r < 4; ++r) {
        int grow = row0 + wm * 64 + i * 16 + (lane >> 4) * 4 + r;   // token
        int gcol = col0 + wn * 64 + j * 16 + rsel;                  // feature
        float v = acc[i][j][r] + bias[gcol] + pos[(size_t)(grow % NTOK) * N + gcol];
        outf[(size_t)grow * N + gcol] = v;
      }
    }
  }
}

// ---------------------------------------------------------------------------
// Fused MoE v4 (r12 + rcp-gelu): 64-token tiles, hi-only weights, 80 KB LDS,
// 2 blocks/CU, operand-swapped MFMAs (lane holds consecutive hid/out per tok).
// ---------------------------------------------------------------------------
__global__ __launch_bounds__(512, 4) void moe_fused(
    const u16* __restrict__ x1h,
    const u16* __restrict__ w1, const u16* __restrict__ w2,
    const float* __restrict__ b1, const float* __restrict__ b2,
    const float* __restrict__ gates,
    const int* __restrict__ idx_all, const int* __restrict__ cnt_all,
    const int* __restrict__ base_all,
    float* __restrict__ yslot)
{
  const int e = blockIdx.z;
  const int Meff = cnt_all[e];
  const int row0 = blockIdx.x * 64;
  if (row0 >= Meff) return;
  const int* gidx = idx_all + (size_t)e * T_TOK;
  const int hbase = base_all[e];
  const u16* W1 = w1 + (size_t)e * 262144;   // [1024][256] (n,k)
  const u16* W2 = w2 + (size_t)e * 262144;   // [256][1024] (n,k)
  const float* B1 = b1 + e * 1024;
  const float* B2 = b2 + e * 256;

  __shared__ u16 Xs[64][256];       // 32 KB, SWZ16
  __shared__ u16 Hs[64][128];       // 16 KB, SWZ4 (row-major [tok][hid])
  __shared__ u16 Ws[2 * 128 * 64];  // 32 KB: ph1 dbuf 2x[128][64]; ph2 flat [256][64]

  const int tid = threadIdx.x, lane = tid & 63, wn = tid >> 6;   // 8 waves
  const int rsel = lane & 15, ksel = (lane >> 4) * 8;
  const f32x4 zero = {0.f, 0.f, 0.f, 0.f};

  const int w1r = tid >> 2, w1c = ((2 * tid) & 7) * 8;
  const int w2r = tid >> 1, w2c = ((4 * tid) & 7) * 8;

  short8 w1a = *(const short8*)(W1 + (size_t)w1r * 256 + w1c);
  short8 w1b = *(const short8*)(W1 + (size_t)w1r * 256 + w1c + 8);
  for (int ch = tid; ch < 2048; ch += 512) {
    int r = ch >> 5, c = (ch & 31) * 8;
    int arr = gidx[min(row0 + r, Meff - 1)];
    *(short8*)&Xs[r][SWZ(r, c)] = *(const short8*)(x1h + (size_t)arr * 256 + c);
  }

  f32x4 acc2[2][4];                 // [out-tile][tok-tile]
#pragma unroll
  for (int i = 0; i < 2; ++i)
#pragma unroll
    for (int j = 0; j < 4; ++j) acc2[i][j] = zero;

  f32x4 acc1[4];                    // [tok-tile]

  // ph1 step: A = W1 slab rows (hid), B = X token tiles. st = k-stage (0..3)
  auto ph1 = [&](int st, int buf) {
#pragma unroll
    for (int kk = 0; kk < 2; ++kk) {
      int wrow = wn * 16 + rsel;
      int wc = kk * 32 + ksel;
      short8 wf = *(const short8*)&Ws[buf * 8192 + wrow * 64 + SWZ(wrow, wc)];
      int kglob = st * 64 + kk * 32 + ksel;
#pragma unroll
      for (int tt = 0; tt < 4; ++tt) {
        int xrow = tt * 16 + rsel;
        short8 xf = *(const short8*)&Xs[xrow][SWZ(xrow, kglob)];
        acc1[tt] = __builtin_amdgcn_mfma_f32_16x16x32_bf16(wf, xf, acc1[tt], 0, 0, 0);
      }
    }
  };
  // ph2 step: A = W2 rows (out), B = H token tiles. st = k-half (0/1)
  auto ph2 = [&](int st) {
#pragma unroll
    for (int kk = 0; kk < 2; ++kk) {
      int wc = kk * 32 + ksel;
      short8 wf[2];
#pragma unroll
      for (int ot = 0; ot < 2; ++ot) {
        int wrow = wn * 32 + ot * 16 + rsel;
        wf[ot] = *(const short8*)&Ws[wrow * 64 + SWZ(wrow, wc)];
      }
      int kc = st * 64 + kk * 32 + ksel;
#pragma unroll
      for (int tt = 0; tt < 4; ++tt) {
        int tok = tt * 16 + rsel;
        short4v lo = *(const short4v*)&Hs[tok][SWZ4(tok, kc)];
        short4v hi = *(const short4v*)&Hs[tok][SWZ4(tok, kc + 4)];
        short8 hf = {lo[0], lo[1], lo[2], lo[3], hi[0], hi[1], hi[2], hi[3]};
#pragma unroll
        for (int ot = 0; ot < 2; ++ot)
          acc2[ot][tt] = __builtin_amdgcn_mfma_f32_16x16x32_bf16(wf[ot], hf, acc2[ot][tt], 0, 0, 0);
      }
    }
  };

  for (int hc = 0; hc < 8; ++hc) {
    const u16* W1c = W1 + (size_t)hc * 128 * 256;
    const u16* W2c = W2 + hc * 128;
    // W2 st0 loads (latency hidden under all of phase 1)
    short8 q0 = *(const short8*)(W2c + (size_t)w2r * 1024 + w2c);
    short8 q1 = *(const short8*)(W2c + (size_t)w2r * 1024 + w2c + 8);
    short8 q2 = *(const short8*)(W2c + (size_t)w2r * 1024 + w2c + 16);
    short8 q3 = *(const short8*)(W2c + (size_t)w2r * 1024 + w2c + 24);

#pragma unroll
    for (int i = 0; i < 4; ++i) acc1[i] = zero;

    // ---- phase 1: 4 stages of BK=64, dbuf ----
    *(short8*)&Ws[w1r * 64 + SWZ(w1r, w1c)] = w1a;
    *(short8*)&Ws[w1r * 64 + SWZ(w1r, w1c + 8)] = w1b;
    short8 p0 = *(const short8*)(W1c + (size_t)w1r * 256 + 64 + w1c);
    short8 p1 = *(const short8*)(W1c + (size_t)w1r * 256 + 64 + w1c + 8);
    __syncthreads();                                           // B1
    short8 s0 = *(const short8*)(W1c + (size_t)w1r * 256 + 128 + w1c);
    short8 s1 = *(const short8*)(W1c + (size_t)w1r * 256 + 128 + w1c + 8);
    ph1(0, 0);
    *(short8*)&Ws[8192 + w1r * 64 + SWZ(w1r, w1c)] = p0;
    *(short8*)&Ws[8192 + w1r * 64 + SWZ(w1r, w1c + 8)] = p1;
    __syncthreads();                                           // B2
    p0 = *(const short8*)(W1c + (size_t)w1r * 256 + 192 + w1c);
    p1 = *(const short8*)(W1c + (size_t)w1r * 256 + 192 + w1c + 8);
    ph1(1, 1);
    *(short8*)&Ws[w1r * 64 + SWZ(w1r, w1c)] = s0;
    *(short8*)&Ws[w1r * 64 + SWZ(w1r, w1c + 8)] = s1;
    __syncthreads();                                           // B3
    ph1(2, 0);
    *(short8*)&Ws[8192 + w1r * 64 + SWZ(w1r, w1c)] = p0;
    *(short8*)&Ws[8192 + w1r * 64 + SWZ(w1r, w1c + 8)] = p1;
    __syncthreads();                                           // B4
    ph1(3, 1);

    // ---- gelu -> Hs (packed ushort4, SWZ4; rcp instead of divide) ----
#pragma unroll
    for (int tt = 0; tt < 4; ++tt) {
      int tok = tt * 16 + rsel;
      int hid0 = wn * 16 + (lane >> 4) * 4;
      u16 hv[4];
#pragma unroll
      for (int r = 0; r < 4; ++r) {
        float v = acc1[tt][r] + B1[hc * 128 + hid0 + r];
        float u = 1.5957691216057308f * (v + 0.044715f * v * v * v);
        float sig = __builtin_amdgcn_rcpf(1.f + __expf(-u));
        hv[r] = bfbits(v * sig);
      }
      *(ushort4*)&Hs[tok][SWZ4(tok, hid0)] = make_ushort4(hv[0], hv[1], hv[2], hv[3]);
    }
    __syncthreads();                                           // B5 (Ws free + Hs ready)

    // ---- phase 2: 2 halves of BK=64, Ws reused flat [256][64] ----
    *(short8*)&Ws[w2r * 64 + SWZ(w2r, w2c)] = q0;
    *(short8*)&Ws[w2r * 64 + SWZ(w2r, w2c + 8)] = q1;
    *(short8*)&Ws[w2r * 64 + SWZ(w2r, w2c + 16)] = q2;
    *(short8*)&Ws[w2r * 64 + SWZ(w2r, w2c + 24)] = q3;
    q0 = *(const short8*)(W2c + (size_t)w2r * 1024 + 64 + w2c);
    q1 = *(const short8*)(W2c + (size_t)w2r * 1024 + 64 + w2c + 8);
    q2 = *(const short8*)(W2c + (size_t)w2r * 1024 + 64 + w2c + 16);
    q3 = *(const short8*)(W2c + (size_t)w2r * 1024 + 64 + w2c + 24);
    __syncthreads();                                           // B6
    ph2(0);
    __syncthreads();                                           // B7
    *(short8*)&Ws[w2r * 64 + SWZ(w2r, w2c)] = q0;
    *(short8*)&Ws[w2r * 64 + SWZ(w2r, w2c + 8)] = q1;
    *(short8*)&Ws[w2r * 64 + SWZ(w2r, w2c + 16)] = q2;
    *(short8*)&Ws[w2r * 64 + SWZ(w2r, w2c + 24)] = q3;
    if (hc < 7) {   // next-hc W1 st0 loads hide under phase-2 st1
      w1a = *(const short8*)(W1 + (size_t)((hc + 1) * 128 + w1r) * 256 + w1c);
      w1b = *(const short8*)(W1 + (size_t)((hc + 1) * 128 + w1r) * 256 + w1c + 8);
    }
    __syncthreads();                                           // B8
    ph2(1);
    __syncthreads();                                           // B9 (Ws+Hs free)
  }

  // ---- epilogue: yslot = gate * (Y + b2), float4 full-line stores ----
#pragma unroll
  for (int tt = 0; tt < 4; ++tt) {
    int grow = row0 + tt * 16 + rsel;
    if (grow < Meff) {
      int tk = gidx[grow];
      float gt = gates[(size_t)tk * 6 + e];
#pragma unroll
      for (int ot = 0; ot < 2; ++ot) {
        int out0 = wn * 32 + ot * 16 + (lane >> 4) * 4;
        float4 w4 = make_float4(gt * (acc2[ot][tt][0] + B2[out0]),
                                gt * (acc2[ot][tt][1] + B2[out0 + 1]),
                                gt * (acc2[ot][tt][2] + B2[out0 + 2]),
                                gt * (acc2[ot][tt][3] + B2[out0 + 3]));
        *(float4*)&yslot[(size_t)(hbase + grow) * 256 + out0] = w4;
      }
    }
  }
}

// ---------------------------------------------------------------------------
// LayerNorm over E=256: wave per token; bf16 out
// ---------------------------------------------------------------------------
__global__ __launch_bounds__(256) void ln_kernel(const float* __restrict__ in,
    const float* __restrict__ g, const float* __restrict__ b, u16* __restrict__ oh)
{
  const int lane = threadIdx.x & 63;
  const int t = blockIdx.x * 4 + (threadIdx.x >> 6);
  const float4 v = *(const float4*)(in + (size_t)t * 256 + lane * 4);
  float s = v.x + v.y + v.z + v.w;
  float sq = v.x * v.x + v.y * v.y + v.z * v.z + v.w * v.w;
#pragma unroll
  for (int o = 32; o >= 1; o >>= 1) {
    s  += __shfl_xor(s,  o, 64);
    sq += __shfl_xor(sq, o, 64);
  }
  float mu = s * (1.f / 256.f);
  float var = sq * (1.f / 256.f) - mu * mu;
  float rstd = rsqrtf(var + 1e-5f);
  const float4 gv = *(const float4*)(g + lane * 4);
  const float4 bv = *(const float4*)(b + lane * 4);
  *(ushort4*)(oh + (size_t)t * 256 + lane * 4) = make_ushort4(
      bfbits((v.x - mu) * rstd * gv.x + bv.x), bfbits((v.y - mu) * rstd * gv.y + bv.y),
      bfbits((v.z - mu) * rstd * gv.z + bv.z), bfbits((v.w - mu) * rstd * gv.w + bv.w));
}

// ---------------------------------------------------------------------------
// Fused slot-combine + LayerNorm: moe[t] = yslot[s0]+yslot[s1]; x2 = LN(moe)
// ---------------------------------------------------------------------------
__global__ __launch_bounds__(256) void ln2_combine(const float* __restrict__ yslot,
    const int* __restrict__ invslot,
    const float* __restrict__ g, const float* __restrict__ b, float* __restrict__ outf)
{
  const int lane = threadIdx.x & 63;
  const int t = blockIdx.x * 4 + (threadIdx.x >> 6);
  const int s0 = invslot[t * 2], s1 = invslot[t * 2 + 1];
  const float4 a = *(const float4*)(yslot + (size_t)s0 * 256 + lane * 4);
  const float4 c = *(const float4*)(yslot + (size_t)s1 * 256 + lane * 4);
  float4 v = make_float4(a.x + c.x, a.y + c.y, a.z + c.z, a.w + c.w);
  float s = v.x + v.y + v.z + v.w;
  float sq = v.x * v.x + v.y * v.y + v.z * v.z + v.w * v.w;
#pragma unroll
  for (int o = 32; o >= 1; o >>= 1) {
    s  += __shfl_xor(s,  o, 64);
    sq += __shfl_xor(sq, o, 64);
  }
  float mu = s * (1.f / 256.f);
  float var = sq * (1.f / 256.f) - mu * mu;
  float rstd = rsqrtf(var + 1e-5f);
  const float4 gv = *(const float4*)(g + lane * 4);
  const float4 bv = *(const float4*)(b + lane * 4);
  *(float4*)(outf + (size_t)t * 256 + lane * 4) = make_float4(
      (v.x - mu) * rstd * gv.x + bv.x, (v.y - mu) * rstd * gv.y + bv.y,
      (v.z - mu) * rstd * gv.z + bv.z, (v.w - mu) * rstd * gv.w + bv.w);
}

// ---------------------------------------------------------------------------
// MFMA attention: one block per (b,h), 4 waves, 13 m-tiles of 16 q-rows.
// ao written split (hi+lo): feeds wo -> x1f -> router (gate precision).
// ---------------------------------------------------------------------------
__global__ __launch_bounds__(256) void attn_mfma(const u16* __restrict__ qkvb,
                                                 u16* __restrict__ aoh, u16* __restrict__ aol) {
  __shared__ u16 Qs[208][40];
  __shared__ u16 Ks[208][40];
  __shared__ u16 Vt[32][256];
  __shared__ u16 Ps[4][16][232];
  const int tid = threadIdx.x, lane = tid & 63, wave = tid >> 6;
  const int b = blockIdx.x >> 3, h = blockIdx.x & 7;
  const size_t base = (size_t)b * 196 * 768 + h * 32;
  const short8 z8 = {0, 0, 0, 0, 0, 0, 0, 0};

  for (int idx = tid; idx < 832; idx += 256) {
    int r = idx >> 2, c = (idx & 3) * 8;
    short8 q = z8, k = z8;
    if (r < 196) {
      q = *(const short8*)(qkvb + base + (size_t)r * 768 + c);
      k = *(const short8*)(qkvb + base + (size_t)r * 768 + 256 + c);
    }
    *(short8*)&Qs[r][c] = q;
    *(short8*)&Ks[r][c] = k;
  }
  for (int idx = tid; idx < 32 * 224; idx += 256) {
    int c = idx & 31, k = idx >> 5;
    u16 v = 0;
    if (k < 196) v = qkvb[base + (size_t)k * 768 + 512 + c];
    Vt[c][k ^ ((c & 7) << 3)] = v;
  }
  {
    int r = lane >> 2, c0 = 208 + (lane & 3) * 4;
    Ps[wave][r][c0] = 0; Ps[wave][r][c0 + 1] = 0; Ps[wave][r][c0 + 2] = 0; Ps[wave][r][c0 + 3] = 0;
  }
  __syncthreads();

  const int rsel = lane & 15, ksel = (lane >> 4) * 8;
  const f32x4 zero = {0.f, 0.f, 0.f, 0.f};

  for (int mt = wave; mt < 13; mt += 4) {
    short8 aq = *(const short8*)&Qs[mt * 16 + rsel][ksel];
    f32x4 sacc[13];
#pragma unroll
    for (int n = 0; n < 13; ++n)
      sacc[n] = __builtin_amdgcn_mfma_f32_16x16x32_bf16(
          aq, *(const short8*)&Ks[n * 16 + rsel][ksel], zero, 0, 0, 0);

#pragma unroll
    for (int r = 0; r < 4; ++r) {
      float mv = -1e30f;
#pragma unroll
      for (int n = 0; n < 13; ++n) {
        float sv = sacc[n][r] * 0.17677669529663687f;
        sacc[n][r] = sv;
        if (n * 16 + rsel < 196) mv = fmaxf(mv, sv);
      }
      mv = fmaxf(mv, __shfl_xor(mv, 1, 64));
      mv = fmaxf(mv, __shfl_xor(mv, 2, 64));
      mv = fmaxf(mv, __shfl_xor(mv, 4, 64));
      mv = fmaxf(mv, __shfl_xor(mv, 8, 64));
      float sm = 0.f;
#pragma unroll
      for (int n = 0; n < 13; ++n) {
        float p = (n * 16 + rsel < 196) ? __expf(sacc[n][r] - mv) : 0.f;
        sacc[n][r] = p;
        sm += p;
      }
      sm += __shfl_xor(sm, 1, 64);
      sm += __shfl_xor(sm, 2, 64);
      sm += __shfl_xor(sm, 4, 64);
      sm += __shfl_xor(sm, 8, 64);
      float inv = __builtin_amdgcn_rcpf(sm);   // P is bf16-rounded next; 1-ulp ok
      int prow = (lane >> 4) * 4 + r;
#pragma unroll
      for (int n = 0; n < 13; ++n)
        Ps[wave][prow][n * 16 + rsel] = bfbits(sacc[n][r] * inv);
    }

    f32x4 oacc[2] = {zero, zero};
#pragma unroll
    for (int kk = 0; kk < 7; ++kk) {
      short8 ap = *(const short8*)&Ps[wave][rsel][kk * 32 + ksel];
#pragma unroll
      for (int nt = 0; nt < 2; ++nt) {
        int d = nt * 16 + rsel;
        short8 bv = *(const short8*)&Vt[d][(kk * 32 + ksel) ^ ((d & 7) << 3)];
        oacc[nt] = __builtin_amdgcn_mfma_f32_16x16x32_bf16(ap, bv, oacc[nt], 0, 0, 0);
      }
    }
#pragma unroll
    for (int nt = 0; nt < 2; ++nt) {
#pragma unroll
      for (int r = 0; r < 4; ++r) {
        int row = mt * 16 + (lane >> 4) * 4 + r;
        if (row < 196) {
          size_t oi = ((size_t)b * 196 + row) * 256 + h * 32 + nt * 16 + rsel;
          u16 hh, ll; fsplit(oacc[nt][r], hh, ll);
          aoh[oi] = hh; aol[oi] = ll;
        }
      }
    }
  }
}

// ---------------------------------------------------------------------------
// Router: wave per token; 6 logits, softmax, top-2 -> dense gates [T,6]
// ---------------------------------------------------------------------------
__global__ __launch_bounds__(256) void router_kernel(const float* __restrict__ x1,
    const float* __restrict__ rw, const float* __restrict__ rb, float* __restrict__ gates)
{
  const int lane = threadIdx.x & 63;
  const int t = blockIdx.x * 4 + (threadIdx.x >> 6);
  const float4 xv = *(const float4*)(x1 + (size_t)t * 256 + lane * 4);
  float logit[6];
#pragma unroll
  for (int e = 0; e < 6; ++e) {
    const float4 wv = *(const float4*)(rw + e * 256 + lane * 4);
    float p = xv.x * wv.x + xv.y * wv.y + xv.z * wv.z + xv.w * wv.w;
#pragma unroll
    for (int o = 32; o >= 1; o >>= 1) p += __shfl_xor(p, o, 64);
    logit[e] = p + rb[e];
  }
  float mx = logit[0];
#pragma unroll
  for (int e = 1; e < 6; ++e) mx = fmaxf(mx, logit[e]);
  float pe[6], sum = 0.f;
#pragma unroll
  for (int e = 0; e < 6; ++e) { pe[e] = __expf(logit[e] - mx); sum += pe[e]; }
  float inv = 1.f / sum;
  int i1 = 0; float p1 = pe[0];
#pragma unroll
  for (int e = 1; e < 6; ++e) if (pe[e] > p1) { p1 = pe[e]; i1 = e; }
  int i2 = -1; float p2 = -1.f;
#pragma unroll
  for (int e = 0; e < 6; ++e) if (e != i1 && pe[e] > p2) { p2 = pe[e]; i2 = e; }
  if (lane < 6)
    gates[(size_t)t * 6 + lane] = (lane == i1) ? p1 * inv : ((lane == i2) ? p2 * inv : 0.f);
}

// ---------------------------------------------------------------------------
// Scatter: build per-expert token lists (block-aggregated atomics)
// ---------------------------------------------------------------------------
__global__ __launch_bounds__(256) void scatter_kernel(const float* __restrict__ gates,
                                                      int* __restrict__ cnt, int* __restrict__ idx) {
  __shared__ int lcnt[6], lbase[6];
  const int t = blockIdx.x * 256 + threadIdx.x;
  if (threadIdx.x < 6) lcnt[threadIdx.x] = 0;
  __syncthreads();
  float g[6]; int lpos[6];
#pragma unroll
  for (int e = 0; e < 6; ++e) {
    g[e] = gates[(size_t)t * 6 + e];
    if (g[e] > 0.f) lpos[e] = atomicAdd(&lcnt[e], 1);
  }
  __syncthreads();
  if (threadIdx.x < 6) lbase[threadIdx.x] = atomicAdd(&cnt[threadIdx.x], lcnt[threadIdx.x]);
  __syncthreads();
#pragma unroll
  for (int e = 0; e < 6; ++e)
    if (g[e] > 0.f) idx[(size_t)e * T_TOK + lbase[e] + lpos[e]] = t;
}

// exclusive prefix over the 6 expert counts -> segment bases in slot buffer
__global__ void prefix6_kernel(const int* __restrict__ cnt, int* __restrict__ base) {
  if (threadIdx.x == 0) {
    int s = 0;
#pragma unroll
    for (int e = 0; e < 6; ++e) { base[e] = s; s += cnt[e]; }
  }
}

// token -> its 2 slot positions in the concatenated expert segments
__global__ __launch_bounds__(256) void slotmap_kernel(const int* __restrict__ idx,
    const int* __restrict__ cnt, const int* __restrict__ base,
    int* __restrict__ nslot, int* __restrict__ invslot) {
  const int e = blockIdx.y;
  const int p = blockIdx.x * 256 + threadIdx.x;
  if (p < cnt[e]) {
    int t = idx[(size_t)e * T_TOK + p];
    int j = atomicAdd(&nslot[t], 1);
    invslot[(size_t)t * 2 + j] = base[e] + p;
  }
}

// ---------------------------------------------------------------------------
// Mean-pool over tokens (fp32)
// ---------------------------------------------------------------------------
__global__ __launch_bounds__(256) void pool_kernel(const float* __restrict__ x2, float* __restrict__ pooled) {
  int b = blockIdx.x, e = threadIdx.x;
  float s = 0.f;
  for (int n = 0; n < 196; ++n) s += x2[((size_t)b * 196 + n) * 256 + e];
  pooled[(size_t)b * 256 + e] = s * (1.f / 196.f);
}

// ---------------------------------------------------------------------------
// Head v2: 32 blocks x 32 classes; pooled[128][256] staged once in LDS,
// hw read exactly once chip-wide. Same fp32 accumulation order per dot.
// ---------------------------------------------------------------------------
__global__ __launch_bounds__(256) void head_kernel(const float* __restrict__ pooled,
    const float* __restrict__ hw, const float* __restrict__ hb, float* __restrict__ out) {
  __shared__ float p[128][257];       // +1 pad
  const int tid = threadIdx.x;
  const int c0 = blockIdx.x * 32;
  for (int i = tid; i < 8192; i += 256) {   // 8192 float4 = 32768 floats
    int b = i >> 6, f = (i & 63) * 4;
    float4 v = *(const float4*)(pooled + (size_t)b * 256 + f);
    p[b][f] = v.x; p[b][f + 1] = v.y; p[b][f + 2] = v.z; p[b][f + 3] = v.w;
  }
  __syncthreads();
  const int cls = c0 + (tid & 31);
  const int b0 = (tid >> 5) * 16;           // 8 groups x 16 batches
  if (cls < 1000) {
    const float* w = hw + (size_t)cls * 256;
    const float bias = hb[cls];
    float acc[16];
#pragma unroll
    for (int j = 0; j < 16; ++j) acc[j] = bias;
    for (int k = 0; k < 256; k += 4) {
      float4 wv = *(const float4*)(w + k);
#pragma unroll
      for (int j = 0; j < 16; ++j)
        acc[j] += p[b0 + j][k] * wv.x + p[b0 + j][k + 1] * wv.y +
                  p[b0 + j][k + 2] * wv.z + p[b0 + j][k + 3] * wv.w;
    }
#pragma unroll
    for (int j = 0; j < 16; ++j)
      out[(size_t)(b0 + j) * 1000 + cls] = acc[j];
  }
}

// ---------------------------------------------------------------------------
// Weight prep: f32 -> hi/lo bf16 split; transpose+cast (hi-only) for MoE
// ---------------------------------------------------------------------------
__global__ void cast_split_kernel(const float* __restrict__ in,
                                  u16* __restrict__ oh, u16* __restrict__ ol, int n4) {
  int id = blockIdx.x * 256 + threadIdx.x;
  if (id >= n4) return;
  float4 v = ((const float4*)in)[id];
  u16 h0, l0, h1, l1, h2, l2, h3, l3;
  fsplit(v.x, h0, l0); fsplit(v.y, h1, l1); fsplit(v.z, h2, l2); fsplit(v.w, h3, l3);
  ((ushort4*)oh)[id] = make_ushort4(h0, h1, h2, h3);
  ((ushort4*)ol)[id] = make_ushort4(l0, l1, l2, l3);
}

__global__ __launch_bounds__(256) void transpose_cast(const float* __restrict__ in,
    u16* __restrict__ oh, int R, int C) {
  __shared__ float tile[32][33];
  const int e = blockIdx.z;
  const int bc = blockIdx.x * 32, br = blockIdx.y * 32;
  const int tx = threadIdx.x & 31, ty = threadIdx.x >> 5;
  const float* src = in + (size_t)e * R * C;
#pragma unroll
  for (int i = 0; i < 32; i += 8)
    tile[ty + i][tx] = src[(size_t)(br + ty + i) * C + bc + tx];
  __syncthreads();
#pragma unroll
  for (int i = 0; i < 32; i += 8) {
    size_t di = (size_t)e * R * C + (size_t)(bc + ty + i) * R + br + tx;
    oh[di] = bfbits(tile[tx][ty + i]);
  }
}

// ---------------------------------------------------------------------------
extern "C" void kernel_launch(void* const* d_in, const int* in_sizes, int n_in,
                              void* d_out, int out_size, void* d_ws, size_t ws_size,
                              hipStream_t stream) {
  (void)in_sizes; (void)n_in; (void)out_size; (void)ws_size;
  const float* x      = (const float*)d_in[0];
  const float* conv_w = (const float*)d_in[1];
  const float* conv_b = (const float*)d_in[2];
  const float* pos    = (const float*)d_in[3];
  const float* ln1_g  = (const float*)d_in[4];
  const float* ln1_b  = (const float*)d_in[5];
  const float* wqkv   = (const float*)d_in[6];
  const float* bqkv   = (const float*)d_in[7];
  const float* wo     = (const float*)d_in[8];
  const float* bo     = (const float*)d_in[9];
  const float* rw     = (const float*)d_in[10];
  const float* rb     = (const float*)d_in[11];
  const float* w1     = (const float*)d_in[12];
  const float* b1     = (const float*)d_in[13];
  const float* w2     = (const float*)d_in[14];
  const float* b2     = (const float*)d_in[15];
  const float* ln2_g  = (const float*)d_in[16];
  const float* ln2_b  = (const float*)d_in[17];
  const float* hw     = (const float*)d_in[18];
  const float* hb     = (const float*)d_in[19];
  float* out = (float*)d_out;

  const int T = T_TOK;
  char* ws = (char*)d_ws;
  size_t off = 0;
  auto alloc = [&](size_t bytes) -> void* {
    void* p = ws + off;
    off += (bytes + 255) & ~(size_t)255;
    return p;
  };
  // region 0: tok+xnh+qkvb -> reused as x2 after qkv consumed
  float* tok    = (float*)alloc((size_t)T * 256 * 4);
  u16*   xnh    = (u16*)  alloc((size_t)T * 256 * 2);
  u16*   qkvb   = (u16*)  alloc((size_t)T * 768 * 2);
  // region 1: aoh+aol+x1f == exactly [2T,256] f32 -> reused as yslot
  u16*   aoh    = (u16*)  alloc((size_t)T * 256 * 2);
  u16*   aol    = (u16*)  alloc((size_t)T * 256 * 2);
  float* x1f    = (float*)alloc((size_t)T * 256 * 4);
  u16*   x1h    = (u16*)  alloc((size_t)T * 256 * 2);
  float* gates  = (float*)alloc((size_t)T * 6 * 4);
  int*   idx    = (int*)  alloc((size_t)6 * T * 4);
  int*   cnt    = (int*)  alloc(256);
  int*   base   = (int*)  alloc(256);
  int*   nslot  = (int*)  alloc((size_t)T * 4);
  int*   invslot= (int*)  alloc((size_t)2 * T * 4);
  float* pooled = (float*)alloc((size_t)128 * 256 * 4);
  u16*   cwh    = (u16*)  alloc((size_t)196608 * 2);
  u16*   cwl    = (u16*)  alloc((size_t)196608 * 2);
  u16*   wqh    = (u16*)  alloc((size_t)196608 * 2);
  u16*   wql    = (u16*)  alloc((size_t)196608 * 2);
  u16*   woh    = (u16*)  alloc((size_t)65536 * 2);
  u16*   wol    = (u16*)  alloc((size_t)65536 * 2);
  u16*   w1th   = (u16*)  alloc((size_t)6 * 262144 * 2);
  u16*   w2th   = (u16*)  alloc((size_t)6 * 262144 * 2);
  // aliases (lifetimes disjoint):
  float* yslot = (float*)aoh;   // [2T,256] f32 (region 1; exact fit)
  float* x2    = (float*)ws;    // [T,256] f32 (region 0 head; tok dead by then)

  // --- weight prep (router-reaching weights hi+lo; MoE weights hi-only) ---
  cast_split_kernel<<<192, 256, 0, stream>>>(conv_w, cwh, cwl, 49152);
  cast_split_kernel<<<192, 256, 0, stream>>>(wqkv, wqh, wql, 49152);
  cast_split_kernel<<<64, 256, 0, stream>>>(wo, woh, wol, 16384);
  transpose_cast<<<dim3(32, 8, 6), 256, 0, stream>>>(w1, w1th, 256, 1024);  // [e][n][k]
  transpose_cast<<<dim3(8, 32, 6), 256, 0, stream>>>(w2, w2th, 1024, 256);  // [e][n][k]

  // --- patch embedding (fused im2col + split-A GEMM) ---
  gemm_patch<<<dim3(196, 2), 256, 0, stream>>>(x, cwh, cwl, conv_b, pos, tok);

  // --- attention block ---
  ln_kernel<<<6272, 256, 0, stream>>>(tok, ln1_g, ln1_b, xnh);
  gemm_bs<5, false><<<dim3(196, 6), 256, 0, stream>>>(xnh, nullptr, wqh, wql, T, 768, 256,
      bqkv, nullptr, nullptr, qkvb);
  attn_mfma<<<1024, 256, 0, stream>>>(qkvb, aoh, aol);
  gemm_bs<2, true><<<dim3(196, 2), 256, 0, stream>>>(aoh, aol, woh, wol, T, 256, 256,
      bo, tok, x1f, x1h);

  // --- MoE (top-2 sparse, fused GEMM1+gelu+GEMM2, 2 blocks/CU) ---
  router_kernel<<<6272, 256, 0, stream>>>(x1f, rw, rb, gates);
  hipMemsetAsync(cnt, 0, 256, stream);
  scatter_kernel<<<98, 256, 0, stream>>>(gates, cnt, idx);
  prefix6_kernel<<<1, 64, 0, stream>>>(cnt, base);
  hipMemsetAsync(nslot, 0, (size_t)T * 4, stream);
  slotmap_kernel<<<dim3(98, 6), 256, 0, stream>>>(idx, cnt, base, nslot, invslot);
  moe_fused<<<dim3(392, 1, 6), 512, 0, stream>>>(x1h, w1th, w2th,
      b1, b2, gates, idx, cnt, base, yslot);

  // --- final norm (fused slot combine), pool, head ---
  ln2_combine<<<6272, 256, 0, stream>>>(yslot, invslot, ln2_g, ln2_b, x2);
  pool_kernel<<<128, 256, 0, stream>>>(x2, pooled);
  head_kernel<<<32, 256, 0, stream>>>(pooled, hw, hb, out);
}